// Round 5
// baseline (966.127 us; speedup 1.0000x reference)
//
#include <hip/hip_runtime.h>
#include <hip/hip_bf16.h>

#define NN 4096
#define NITER 6
#define NSWEEP 5
#define NBLK 1024          // blocks in CG step kernels
#define CS 72              // Wc column stride in words (288B, 16B-aligned)
#define WIDX(r) (((r)&31) + 36*((r)>>5))   // element row->word within a column

// workspace float layout
#define OFF_STS  64               // StS[4096]
#define OFF_QRHO (OFF_STS + NN)
#define OFF_DINV (OFF_QRHO + NN)
#define OFF_X    (OFF_DINV + NN)
#define OFF_R    (OFF_X + NN)
#define OFF_P    (OFF_R + NN)
#define OFF_Y    (OFF_P + NN)
// wf[0]=pTy acc, wf[1]=rz acc, ((uint*)wf)[2]=block counter
#define DH_OFF_BYTES 131072
#define WS_NEED_BF16 (DH_OFF_BYTES + (size_t)NN * NN * 2)

typedef unsigned int uint;
__device__ inline float lo2f(uint w){ return __uint_as_float(w << 16); }
__device__ inline float hi2f(uint w){ return __uint_as_float(w & 0xffff0000u); }
__device__ inline uint f2b(float f){
    uint u = __float_as_uint(f);
    return (u + 0x7FFFu + ((u >> 16) & 1u)) >> 16;   // RNE
}

// ---------------- prep: StS + b + approx diag + CG init (k_sts folded in) ----------------
__global__ void k_prep(const float* __restrict__ inp, const float* __restrict__ L,
                       const int*  __restrict__ mask, const float* __restrict__ thP,
                       const float* __restrict__ S,
                       const float* __restrict__ l2p, const float* __restrict__ rhop,
                       float* __restrict__ wf){
    int t = blockIdx.x * 256 + threadIdx.x;   // 4096 threads
    int r = t >> 6, c = t & 63;
    // StS[r][c] and column norm StS[c][c] in one stream
    float acc = 0.f, acc2 = 0.f;
    for(int h = 0; h < 64; ++h){
        float sr = S[h*64 + r];     // scalar per wave (r uniform in wave)
        float sc = S[h*64 + c];     // coalesced
        acc  += sr * sc;
        acc2 += sc * sc;
    }
    wf[OFF_STS + t] = acc;
    float rho = rhop[0], l2 = l2p[0];
    float q = (mask[t] != 0) ? 1.f : 0.f;
    float bi = rho * (L[t] - thP[t]) + q * inp[t];
    // preconditioner diag (drop tiny l1*D_ii term; exact A still in matvec)
    float dinv = 1.f / (q + rho + l2 * acc2);
    wf[OFF_QRHO + t] = q + rho;
    wf[OFF_DINV + t] = dinv;
    wf[OFF_X + t]    = 0.f;
    wf[OFF_R + t]    = bi;
    float z = bi * dinv;
    wf[OFF_P + t]    = z;
    float part = bi * z;
    for(int m = 32; m >= 1; m >>= 1) part += __shfl_xor(part, m, 64);
    __shared__ float red[4];
    int wave = threadIdx.x >> 6, lane = threadIdx.x & 63;
    if(lane == 0) red[wave] = part;
    __syncthreads();
    if(threadIdx.x == 0) atomicAdd(&wf[1], red[0] + red[1] + red[2] + red[3]);
}

// ---------------- CG update performed by the last-arriving block ----------------
__device__ void cg_update(float* __restrict__ wf){
    __shared__ float lds2[4];
    int tid = threadIdx.x;
    float pTy = atomicAdd(&wf[0], 0.0f);   // coherent read
    float rz  = wf[1];
    float alpha = rz / pTy;
    float* x = wf + OFF_X;
    float* r = wf + OFF_R;
    float* p = wf + OFF_P;
    const float* y    = wf + OFF_Y;
    const float* dinv = wf + OFF_DINV;
    int i0 = tid * 16;
    float part = 0.f;
    float zi[16], pi[16];
    #pragma unroll
    for(int k = 0; k < 16; ++k){
        int i = i0 + k;
        float pv = p[i]; pi[k] = pv;
        x[i] += alpha * pv;
        float rv = r[i] - alpha * y[i];
        r[i] = rv;
        float z = rv * dinv[i]; zi[k] = z;
        part += rv * z;
    }
    for(int m = 32; m >= 1; m >>= 1) part += __shfl_xor(part, m, 64);
    int wave = tid >> 6, lane = tid & 63;
    if(lane == 0) lds2[wave] = part;
    __syncthreads();
    float rznew = lds2[0] + lds2[1] + lds2[2] + lds2[3];
    float beta = rznew / rz;
    #pragma unroll
    for(int k = 0; k < 16; ++k) p[i0 + k] = zi[k] + beta * pi[k];
    if(tid == 0){ wf[1] = rznew; wf[0] = 0.f; ((uint*)wf)[2] = 0u; }
}

// common tail: mark done, last block updates
__device__ void step_tail(float* __restrict__ wf){
    __shared__ uint isLast;
    __threadfence();                               // release y + pTy atomic
    if(threadIdx.x == 0){
        uint old = atomicAdd(&((uint*)wf)[2], 1u);
        isLast = (old == (uint)(NBLK - 1)) ? 1u : 0u;
    }
    __syncthreads();
    if(isLast){
        __threadfence();                           // acquire
        cg_update(wf);
    }
}

// ---------------- CG step, bf16 D ----------------
__launch_bounds__(256)
__global__ void k_step_h(const unsigned short* __restrict__ Dh,
                         const float* __restrict__ l1p, const float* __restrict__ l2p,
                         float* __restrict__ wf){
    __shared__ float psh[NN];
    __shared__ float red[4];
    const float* p    = wf + OFF_P;
    const float* qrho = wf + OFF_QRHO;
    const float* StS  = wf + OFF_STS;
    float* y          = wf + OFF_Y;
    int tid = threadIdx.x;
    const float4* p4 = (const float4*)p;
    float4* psh4 = (float4*)psh;
    for(int k = 0; k < 4; ++k) psh4[tid + k*256] = p4[tid + k*256];
    __syncthreads();

    float l1 = l1p[0], l2 = l2p[0];
    int wave = tid >> 6, lane = tid & 63;
    int row = blockIdx.x * 4 + wave;
    int h = row >> 6, u = row & 63;

    const unsigned short* Drow = Dh + (size_t)row * NN;
    float dacc = 0.f;
    for(int j = 0; j < 8; ++j){
        int c0 = j*512 + lane*8;
        uint4 dv = *(const uint4*)(Drow + c0);
        float4 pa = *(const float4*)(psh + c0);
        float4 pb = *(const float4*)(psh + c0 + 4);
        dacc += lo2f(dv.x)*pa.x + hi2f(dv.x)*pa.y
              + lo2f(dv.y)*pa.z + hi2f(dv.y)*pa.w
              + lo2f(dv.z)*pb.x + hi2f(dv.z)*pb.y
              + lo2f(dv.w)*pb.z + hi2f(dv.w)*pb.w;
    }
    float sacc = StS[u*64 + lane] * psh[h*64 + lane];
    float val = l1 * dacc + l2 * sacc;
    for(int m = 32; m >= 1; m >>= 1) val += __shfl_xor(val, m, 64);
    if(lane == 0){
        float yi = val + qrho[row] * psh[row];
        y[row] = yi;
        red[wave] = yi * psh[row];
    }
    __syncthreads();
    if(tid == 0) atomicAdd(&wf[0], red[0] + red[1] + red[2] + red[3]);
    step_tail(wf);
}

// ---------------- CG step 0: fp32 D + emit bf16 Dh ----------------
__launch_bounds__(256)
__global__ void k_step_fc(const float* __restrict__ D, unsigned short* __restrict__ Dh,
                          const float* __restrict__ l1p, const float* __restrict__ l2p,
                          float* __restrict__ wf){
    __shared__ float psh[NN];
    __shared__ float red[4];
    const float* p    = wf + OFF_P;
    const float* qrho = wf + OFF_QRHO;
    const float* StS  = wf + OFF_STS;
    float* y          = wf + OFF_Y;
    int tid = threadIdx.x;
    const float4* p4 = (const float4*)p;
    float4* psh4 = (float4*)psh;
    for(int k = 0; k < 4; ++k) psh4[tid + k*256] = p4[tid + k*256];
    __syncthreads();

    float l1 = l1p[0], l2 = l2p[0];
    int wave = tid >> 6, lane = tid & 63;
    int row = blockIdx.x * 4 + wave;
    int h = row >> 6, u = row & 63;

    const float* Drow = D + (size_t)row * NN;
    unsigned short* Dhrow = Dh + (size_t)row * NN;
    float dacc = 0.f;
    for(int j = 0; j < 16; ++j){
        int c0 = j*256 + lane*4;
        float4 dv = *(const float4*)(Drow + c0);
        float4 pa = *(const float4*)(psh + c0);
        dacc += dv.x*pa.x + dv.y*pa.y + dv.z*pa.z + dv.w*pa.w;
        uint2 o;
        o.x = f2b(dv.x) | (f2b(dv.y) << 16);
        o.y = f2b(dv.z) | (f2b(dv.w) << 16);
        *(uint2*)(Dhrow + c0) = o;
    }
    float sacc = StS[u*64 + lane] * psh[h*64 + lane];
    float val = l1 * dacc + l2 * sacc;
    for(int m = 32; m >= 1; m >>= 1) val += __shfl_xor(val, m, 64);
    if(lane == 0){
        float yi = val + qrho[row] * psh[row];
        y[row] = yi;
        red[wave] = yi * psh[row];
    }
    __syncthreads();
    if(tid == 0) atomicAdd(&wf[0], red[0] + red[1] + red[2] + red[3]);
    step_tail(wf);
}

// ---------------- CG step, fp32 D fallback ----------------
__launch_bounds__(256)
__global__ void k_step_f(const float* __restrict__ D,
                         const float* __restrict__ l1p, const float* __restrict__ l2p,
                         float* __restrict__ wf){
    __shared__ float psh[NN];
    __shared__ float red[4];
    const float* p    = wf + OFF_P;
    const float* qrho = wf + OFF_QRHO;
    const float* StS  = wf + OFF_STS;
    float* y          = wf + OFF_Y;
    int tid = threadIdx.x;
    const float4* p4 = (const float4*)p;
    float4* psh4 = (float4*)psh;
    for(int k = 0; k < 4; ++k) psh4[tid + k*256] = p4[tid + k*256];
    __syncthreads();

    float l1 = l1p[0], l2 = l2p[0];
    int wave = tid >> 6, lane = tid & 63;
    int row = blockIdx.x * 4 + wave;
    int h = row >> 6, u = row & 63;

    const float* Drow = D + (size_t)row * NN;
    float dacc = 0.f;
    for(int j = 0; j < 16; ++j){
        int c0 = j*256 + lane*4;
        float4 dv = *(const float4*)(Drow + c0);
        float4 pa = *(const float4*)(psh + c0);
        dacc += dv.x*pa.x + dv.y*pa.y + dv.z*pa.z + dv.w*pa.w;
    }
    float sacc = StS[u*64 + lane] * psh[h*64 + lane];
    float val = l1 * dacc + l2 * sacc;
    for(int m = 32; m >= 1; m >>= 1) val += __shfl_xor(val, m, 64);
    if(lane == 0){
        float yi = val + qrho[row] * psh[row];
        y[row] = yi;
        red[wave] = yi * psh[row];
    }
    __syncthreads();
    if(tid == 0) atomicAdd(&wf[0], red[0] + red[1] + red[2] + red[3]);
    step_tail(wf);
}

// ---------------- SVT: single-wave one-sided Jacobi (no barriers in sweep) ----------------
// W = U diag(s) after convergence. Ltmp = W diag(relu(s-thr)/s^3) (W^T X).
__launch_bounds__(256)
__global__ void k_svt(const float* __restrict__ thP, const float* __restrict__ vp,
                      const float* __restrict__ netap,
                      const float* __restrict__ wf, float* __restrict__ out){
    __shared__ float Wc[64*CS];   // element (r,c) at Wc[c*CS + WIDX(r)]
    __shared__ float Xsh[NN];     // row-major
    __shared__ float Tsh[NN];
    __shared__ float s2[64], coef3[64];
    __shared__ float smax_sh;
    int tid = threadIdx.x;
    const float* x = wf + OFF_X;

    for(int k = 0; k < 16; ++k){
        int n = tid + k*256;
        int r = n >> 6, c = n & 63;
        float v = x[n] + thP[n];
        Xsh[n] = v;
        Wc[c*CS + WIDX(r)] = v;
    }
    __syncthreads();

    // sweeps: wave 0 only, 32 pairs x 2 lanes, 32 elements (8 float4) per lane per column
    if(tid < 64){
        int g  = tid >> 1;        // pair 0..31
        int hf = tid & 1;         // half: rows 32*hf..32*hf+31
        int hofs = 36 * hf;
        for(int sweep = 0; sweep < NSWEEP; ++sweep){
          for(int rnd = 0; rnd < 63; ++rnd){
            int p, q;
            if(g == 0){ p = 63; q = rnd; }
            else { p = (rnd + g) % 63; q = (rnd + 63 - g) % 63; }
            float4* Wp = (float4*)(Wc + p*CS + hofs);
            float4* Wq = (float4*)(Wc + q*CS + hofs);
            float4 a0=Wp[0],a1=Wp[1],a2=Wp[2],a3=Wp[3],a4=Wp[4],a5=Wp[5],a6=Wp[6],a7=Wp[7];
            float4 b0=Wq[0],b1=Wq[1],b2=Wq[2],b3=Wq[3],b4=Wq[4],b5=Wq[5],b6=Wq[6],b7=Wq[7];
            float aa = a0.x*a0.x+a0.y*a0.y+a0.z*a0.z+a0.w*a0.w + a1.x*a1.x+a1.y*a1.y+a1.z*a1.z+a1.w*a1.w
                     + a2.x*a2.x+a2.y*a2.y+a2.z*a2.z+a2.w*a2.w + a3.x*a3.x+a3.y*a3.y+a3.z*a3.z+a3.w*a3.w
                     + a4.x*a4.x+a4.y*a4.y+a4.z*a4.z+a4.w*a4.w + a5.x*a5.x+a5.y*a5.y+a5.z*a5.z+a5.w*a5.w
                     + a6.x*a6.x+a6.y*a6.y+a6.z*a6.z+a6.w*a6.w + a7.x*a7.x+a7.y*a7.y+a7.z*a7.z+a7.w*a7.w;
            float bb = b0.x*b0.x+b0.y*b0.y+b0.z*b0.z+b0.w*b0.w + b1.x*b1.x+b1.y*b1.y+b1.z*b1.z+b1.w*b1.w
                     + b2.x*b2.x+b2.y*b2.y+b2.z*b2.z+b2.w*b2.w + b3.x*b3.x+b3.y*b3.y+b3.z*b3.z+b3.w*b3.w
                     + b4.x*b4.x+b4.y*b4.y+b4.z*b4.z+b4.w*b4.w + b5.x*b5.x+b5.y*b5.y+b5.z*b5.z+b5.w*b5.w
                     + b6.x*b6.x+b6.y*b6.y+b6.z*b6.z+b6.w*b6.w + b7.x*b7.x+b7.y*b7.y+b7.z*b7.z+b7.w*b7.w;
            float cc = a0.x*b0.x+a0.y*b0.y+a0.z*b0.z+a0.w*b0.w + a1.x*b1.x+a1.y*b1.y+a1.z*b1.z+a1.w*b1.w
                     + a2.x*b2.x+a2.y*b2.y+a2.z*b2.z+a2.w*b2.w + a3.x*b3.x+a3.y*b3.y+a3.z*b3.z+a3.w*b3.w
                     + a4.x*b4.x+a4.y*b4.y+a4.z*b4.z+a4.w*b4.w + a5.x*b5.x+a5.y*b5.y+a5.z*b5.z+a5.w*b5.w
                     + a6.x*b6.x+a6.y*b6.y+a6.z*b6.z+a6.w*b6.w + a7.x*b7.x+a7.y*b7.y+a7.z*b7.z+a7.w*b7.w;
            aa += __shfl_xor(aa, 1);
            bb += __shfl_xor(bb, 1);
            cc += __shfl_xor(cc, 1);
            if(fabsf(cc) > 1e-30f){
                float zeta = (bb - aa) / (2.f * cc);
                float t = copysignf(1.f / (fabsf(zeta) + sqrtf(1.f + zeta*zeta)), zeta);
                float cs = rsqrtf(1.f + t*t);
                float sn = t * cs;
                float4 na, nb;
                #define ROT(A,B,I) \
                    na.x = cs*A.x - sn*B.x; na.y = cs*A.y - sn*B.y; \
                    na.z = cs*A.z - sn*B.z; na.w = cs*A.w - sn*B.w; \
                    nb.x = sn*A.x + cs*B.x; nb.y = sn*A.y + cs*B.y; \
                    nb.z = sn*A.z + cs*B.z; nb.w = sn*A.w + cs*B.w; \
                    Wp[I] = na; Wq[I] = nb;
                ROT(a0,b0,0) ROT(a1,b1,1) ROT(a2,b2,2) ROT(a3,b3,3)
                ROT(a4,b4,4) ROT(a5,b5,5) ROT(a6,b6,6) ROT(a7,b7,7)
                #undef ROT
            }
            asm volatile("s_waitcnt lgkmcnt(0)" ::: "memory");   // wave-sync LDS RAW
          }
        }
    }
    __syncthreads();   // waves 1-3 were parked here

    // column norms
    if(tid < 64){
        float acc = 0.f;
        const float* col = Wc + tid*CS;
        #pragma unroll
        for(int r = 0; r < 32; ++r){ float w = col[r]; acc += w*w; }
        #pragma unroll
        for(int r = 0; r < 32; ++r){ float w = col[36 + r]; acc += w*w; }
        s2[tid] = acc;
    }
    __syncthreads();
    if(tid == 0){
        float sm = 0.f;
        for(int c = 0; c < 64; ++c) sm = fmaxf(sm, s2[c]);
        smax_sh = sqrtf(sm);
    }
    __syncthreads();
    if(tid < 64){
        float s = sqrtf(s2[tid]);
        float v = vp[0];
        float tau = 0.4f / (1.f + expf(-v));    // sigmoid(v)*COEF_GAMMA
        float thr = tau * smax_sh;
        coef3[tid] = (s > thr && s > 1e-20f) ? (s - thr) / (s*s*s) : 0.f;
    }
    __syncthreads();

    // R1: T'[k][j] = coef3[k] * sum_r W[r][k] * Xsh[r][j]
    {
        int kk = tid >> 2;
        int j0 = (tid & 3) * 16;
        float acc[16];
        #pragma unroll
        for(int j = 0; j < 16; ++j) acc[j] = 0.f;
        for(int r = 0; r < 64; ++r){
            float wk = Wc[kk*CS + WIDX(r)];
            const float* xr = Xsh + r*64 + j0;
            float4 x0 = *(const float4*)(xr);
            float4 x1 = *(const float4*)(xr + 4);
            float4 x2 = *(const float4*)(xr + 8);
            float4 x3 = *(const float4*)(xr + 12);
            acc[0]+=wk*x0.x; acc[1]+=wk*x0.y; acc[2]+=wk*x0.z; acc[3]+=wk*x0.w;
            acc[4]+=wk*x1.x; acc[5]+=wk*x1.y; acc[6]+=wk*x1.z; acc[7]+=wk*x1.w;
            acc[8]+=wk*x2.x; acc[9]+=wk*x2.y; acc[10]+=wk*x2.z; acc[11]+=wk*x2.w;
            acc[12]+=wk*x3.x; acc[13]+=wk*x3.y; acc[14]+=wk*x3.z; acc[15]+=wk*x3.w;
        }
        float c3 = coef3[kk];
        float* tr = Tsh + kk*64 + j0;
        #pragma unroll
        for(int j = 0; j < 16; ++j) tr[j] = c3 * acc[j];
    }
    __syncthreads();

    // R2: Ltmp[i][j] = sum_k W[i][k] * T'[k][j]; outputs
    {
        int i  = tid >> 2;
        int j0 = (tid & 3) * 16;
        float acc[16];
        #pragma unroll
        for(int j = 0; j < 16; ++j) acc[j] = 0.f;
        for(int kk = 0; kk < 64; ++kk){
            float wik = Wc[kk*CS + WIDX(i)];
            const float* tr = Tsh + kk*64 + j0;
            float4 t0 = *(const float4*)(tr);
            float4 t1 = *(const float4*)(tr + 4);
            float4 t2 = *(const float4*)(tr + 8);
            float4 t3 = *(const float4*)(tr + 12);
            acc[0]+=wik*t0.x; acc[1]+=wik*t0.y; acc[2]+=wik*t0.z; acc[3]+=wik*t0.w;
            acc[4]+=wik*t1.x; acc[5]+=wik*t1.y; acc[6]+=wik*t1.z; acc[7]+=wik*t1.w;
            acc[8]+=wik*t2.x; acc[9]+=wik*t2.y; acc[10]+=wik*t2.z; acc[11]+=wik*t2.w;
            acc[12]+=wik*t3.x; acc[13]+=wik*t3.y; acc[14]+=wik*t3.z; acc[15]+=wik*t3.w;
        }
        float neta = netap[0];
        int n0 = i*64 + j0;
        #pragma unroll
        for(int c = 0; c < 4; ++c){
            float4 th = *(const float4*)(thP + n0 + 4*c);
            float4 lt, pt;
            lt.x = acc[4*c+0]; lt.y = acc[4*c+1]; lt.z = acc[4*c+2]; lt.w = acc[4*c+3];
            float4 xs = *(const float4*)(Xsh + n0 + 4*c);
            pt.x = th.x + neta * (xs.x - th.x - lt.x);
            pt.y = th.y + neta * (xs.y - th.y - lt.y);
            pt.z = th.z + neta * (xs.z - th.z - lt.z);
            pt.w = th.w + neta * (xs.w - th.w - lt.w);
            *(float4*)(out + n0 + 4*c)      = lt;
            *(float4*)(out + NN + n0 + 4*c) = pt;
        }
    }
}

extern "C" void kernel_launch(void* const* d_in, const int* in_sizes, int n_in,
                              void* d_out, int out_size, void* d_ws, size_t ws_size,
                              hipStream_t stream){
    const float* inp  = (const float*)d_in[0];
    const float* L    = (const float*)d_in[1];
    const int*   mask = (const int*)  d_in[2];
    const float* D    = (const float*)d_in[3];
    const float* thP  = (const float*)d_in[4];
    const float* vS   = (const float*)d_in[5];
    const float* neta = (const float*)d_in[6];
    const float* l1   = (const float*)d_in[7];
    const float* l2   = (const float*)d_in[8];
    const float* rho  = (const float*)d_in[9];
    const float* S    = (const float*)d_in[10];
    float* wf = (float*)d_ws;
    float* out = (float*)d_out;
    const bool use_bf16 = (ws_size >= WS_NEED_BF16);
    unsigned short* Dh = (unsigned short*)((char*)d_ws + DH_OFF_BYTES);

    hipMemsetAsync(d_ws, 0, 64 * sizeof(float), stream);   // zero pTy/rz/counter
    k_prep<<<16, 256, 0, stream>>>(inp, L, mask, thP, S, l2, rho, wf);
    if(use_bf16){
        k_step_fc<<<NBLK, 256, 0, stream>>>(D, Dh, l1, l2, wf);
        for(int it = 1; it < NITER; ++it)
            k_step_h<<<NBLK, 256, 0, stream>>>(Dh, l1, l2, wf);
    } else {
        for(int it = 0; it < NITER; ++it)
            k_step_f<<<NBLK, 256, 0, stream>>>(D, l1, l2, wf);
    }
    k_svt<<<1, 256, 0, stream>>>(thP, vS, neta, wf, out);
}

// Round 6
// 480.229 us; speedup vs baseline: 2.0118x; 2.0118x over previous
//
#include <hip/hip_runtime.h>
#include <hip/hip_bf16.h>

#define NN 4096
#define NITER 5
#define NSWEEP 5
#define MCS 68     // mailbox/Wc column stride (floats): 272B, 16B-aligned, scatters banks

// workspace float layout
#define OFF_STS  64
#define OFF_QRHO (OFF_STS + NN)
#define OFF_DINV (OFF_QRHO + NN)
#define OFF_X    (OFF_DINV + NN)
#define OFF_R    (OFF_X + NN)
#define OFF_P    (OFF_R + NN)
#define OFF_Y    (OFF_P + NN)
// wf[0]=pTy acc, wf[1]=rz acc
#define DH_OFF_BYTES 131072
#define WS_NEED_BF16 (DH_OFF_BYTES + (size_t)NN * NN * 2)

typedef unsigned int uint;
__device__ inline float lo2f(uint w){ return __uint_as_float(w << 16); }
__device__ inline float hi2f(uint w){ return __uint_as_float(w & 0xffff0000u); }
__device__ inline uint f2b(float f){
    uint u = __float_as_uint(f);
    return (u + 0x7FFFu + ((u >> 16) & 1u)) >> 16;   // RNE
}

// ---------------- prep: StS + b + approx diag + CG init ----------------
__global__ void k_prep(const float* __restrict__ inp, const float* __restrict__ L,
                       const int*  __restrict__ mask, const float* __restrict__ thP,
                       const float* __restrict__ S,
                       const float* __restrict__ l2p, const float* __restrict__ rhop,
                       float* __restrict__ wf){
    int t = blockIdx.x * 256 + threadIdx.x;   // 4096 threads
    int r = t >> 6, c = t & 63;
    float acc = 0.f, acc2 = 0.f;
    for(int h = 0; h < 64; ++h){
        float sr = S[h*64 + r];
        float sc = S[h*64 + c];
        acc  += sr * sc;
        acc2 += sc * sc;
    }
    wf[OFF_STS + t] = acc;
    float rho = rhop[0], l2 = l2p[0];
    float q = (mask[t] != 0) ? 1.f : 0.f;
    float bi = rho * (L[t] - thP[t]) + q * inp[t];
    float dinv = 1.f / (q + rho + l2 * acc2);   // preconditioner only (l1*D_ii dropped)
    wf[OFF_QRHO + t] = q + rho;
    wf[OFF_DINV + t] = dinv;
    wf[OFF_X + t]    = 0.f;
    wf[OFF_R + t]    = bi;
    float z = bi * dinv;
    wf[OFF_P + t]    = z;
    float part = bi * z;
    for(int m = 32; m >= 1; m >>= 1) part += __shfl_xor(part, m, 64);
    __shared__ float red[4];
    int wave = threadIdx.x >> 6, lane = threadIdx.x & 63;
    if(lane == 0) red[wave] = part;
    __syncthreads();
    if(threadIdx.x == 0) atomicAdd(&wf[1], red[0] + red[1] + red[2] + red[3]);
}

// ---------------- iter 0: y = A p from fp32 D + emit bf16 Dh ----------------
__launch_bounds__(256)
__global__ void k_matvec_fc(const float* __restrict__ D, unsigned short* __restrict__ Dh,
                            const float* __restrict__ l1p, const float* __restrict__ l2p,
                            float* __restrict__ wf){
    __shared__ float psh[NN];
    __shared__ float red[4];
    const float* p    = wf + OFF_P;
    const float* qrho = wf + OFF_QRHO;
    const float* StS  = wf + OFF_STS;
    float* y          = wf + OFF_Y;
    int tid = threadIdx.x;
    const float4* p4 = (const float4*)p;
    float4* psh4 = (float4*)psh;
    for(int k = 0; k < 4; ++k) psh4[tid + k*256] = p4[tid + k*256];
    __syncthreads();

    float l1 = l1p[0], l2 = l2p[0];
    int wave = tid >> 6, lane = tid & 63;
    int row = blockIdx.x * 4 + wave;
    int h = row >> 6, u = row & 63;

    const float* Drow = D + (size_t)row * NN;
    unsigned short* Dhrow = Dh + (size_t)row * NN;
    float dacc = 0.f;
    for(int j = 0; j < 16; ++j){
        int c0 = j*256 + lane*4;
        float4 dv = *(const float4*)(Drow + c0);
        float4 pa = *(const float4*)(psh + c0);
        dacc += dv.x*pa.x + dv.y*pa.y + dv.z*pa.z + dv.w*pa.w;
        uint2 o;
        o.x = f2b(dv.x) | (f2b(dv.y) << 16);
        o.y = f2b(dv.z) | (f2b(dv.w) << 16);
        *(uint2*)(Dhrow + c0) = o;
    }
    float sacc = StS[u*64 + lane] * psh[h*64 + lane];
    float val = l1 * dacc + l2 * sacc;
    for(int m = 32; m >= 1; m >>= 1) val += __shfl_xor(val, m, 64);
    if(lane == 0){
        float yi = val + qrho[row] * psh[row];
        y[row] = yi;
        red[wave] = yi * psh[row];
    }
    __syncthreads();
    if(tid == 0) atomicAdd(&wf[0], red[0] + red[1] + red[2] + red[3]);
}

// ---------------- y = A p (bf16 D) ----------------
__launch_bounds__(256)
__global__ void k_matvec_h(const unsigned short* __restrict__ Dh,
                           const float* __restrict__ l1p, const float* __restrict__ l2p,
                           float* __restrict__ wf){
    __shared__ float psh[NN];
    __shared__ float red[4];
    const float* p    = wf + OFF_P;
    const float* qrho = wf + OFF_QRHO;
    const float* StS  = wf + OFF_STS;
    float* y          = wf + OFF_Y;
    int tid = threadIdx.x;
    const float4* p4 = (const float4*)p;
    float4* psh4 = (float4*)psh;
    for(int k = 0; k < 4; ++k) psh4[tid + k*256] = p4[tid + k*256];
    __syncthreads();

    float l1 = l1p[0], l2 = l2p[0];
    int wave = tid >> 6, lane = tid & 63;
    int row = blockIdx.x * 4 + wave;
    int h = row >> 6, u = row & 63;

    const unsigned short* Drow = Dh + (size_t)row * NN;
    float dacc = 0.f;
    for(int j = 0; j < 8; ++j){
        int c0 = j*512 + lane*8;
        uint4 dv = *(const uint4*)(Drow + c0);
        float4 pa = *(const float4*)(psh + c0);
        float4 pb = *(const float4*)(psh + c0 + 4);
        dacc += lo2f(dv.x)*pa.x + hi2f(dv.x)*pa.y
              + lo2f(dv.y)*pa.z + hi2f(dv.y)*pa.w
              + lo2f(dv.z)*pb.x + hi2f(dv.z)*pb.y
              + lo2f(dv.w)*pb.z + hi2f(dv.w)*pb.w;
    }
    float sacc = StS[u*64 + lane] * psh[h*64 + lane];
    float val = l1 * dacc + l2 * sacc;
    for(int m = 32; m >= 1; m >>= 1) val += __shfl_xor(val, m, 64);
    if(lane == 0){
        float yi = val + qrho[row] * psh[row];
        y[row] = yi;
        red[wave] = yi * psh[row];
    }
    __syncthreads();
    if(tid == 0) atomicAdd(&wf[0], red[0] + red[1] + red[2] + red[3]);
}

// ---------------- y = A p (fp32 fallback) ----------------
__launch_bounds__(256)
__global__ void k_matvec_f(const float* __restrict__ D,
                           const float* __restrict__ l1p, const float* __restrict__ l2p,
                           float* __restrict__ wf){
    __shared__ float psh[NN];
    __shared__ float red[4];
    const float* p    = wf + OFF_P;
    const float* qrho = wf + OFF_QRHO;
    const float* StS  = wf + OFF_STS;
    float* y          = wf + OFF_Y;
    int tid = threadIdx.x;
    const float4* p4 = (const float4*)p;
    float4* psh4 = (float4*)psh;
    for(int k = 0; k < 4; ++k) psh4[tid + k*256] = p4[tid + k*256];
    __syncthreads();
    float l1 = l1p[0], l2 = l2p[0];
    int wave = tid >> 6, lane = tid & 63;
    int row = blockIdx.x * 4 + wave;
    int h = row >> 6, u = row & 63;
    const float* Drow = D + (size_t)row * NN;
    float dacc = 0.f;
    for(int j = 0; j < 16; ++j){
        int c0 = j*256 + lane*4;
        float4 dv = *(const float4*)(Drow + c0);
        float4 pa = *(const float4*)(psh + c0);
        dacc += dv.x*pa.x + dv.y*pa.y + dv.z*pa.z + dv.w*pa.w;
    }
    float sacc = StS[u*64 + lane] * psh[h*64 + lane];
    float val = l1 * dacc + l2 * sacc;
    for(int m = 32; m >= 1; m >>= 1) val += __shfl_xor(val, m, 64);
    if(lane == 0){
        float yi = val + qrho[row] * psh[row];
        y[row] = yi;
        red[wave] = yi * psh[row];
    }
    __syncthreads();
    if(tid == 0) atomicAdd(&wf[0], red[0] + red[1] + red[2] + red[3]);
}

// ---------------- CG scalar/vector update (one block) ----------------
__launch_bounds__(1024)
__global__ void k_cgupd(float* __restrict__ wf){
    __shared__ float lds[16];
    int tid = threadIdx.x;
    float pTy = wf[0], rz = wf[1];
    float alpha = rz / pTy;
    float* x = wf + OFF_X;
    float* r = wf + OFF_R;
    float* p = wf + OFF_P;
    const float* y    = wf + OFF_Y;
    const float* dinv = wf + OFF_DINV;
    float zi[4], pi[4];
    float part = 0.f;
    for(int k = 0; k < 4; ++k){
        int i = tid + k*1024;
        float pv = p[i]; pi[k] = pv;
        x[i] += alpha * pv;
        float rv = r[i] - alpha * y[i];
        r[i] = rv;
        float z = rv * dinv[i]; zi[k] = z;
        part += rv * z;
    }
    for(int m = 32; m >= 1; m >>= 1) part += __shfl_xor(part, m, 64);
    int wave = tid >> 6, lane = tid & 63;
    if(lane == 0) lds[wave] = part;
    __syncthreads();
    float rznew = 0.f;
    for(int w = 0; w < 16; ++w) rznew += lds[w];
    float beta = rznew / rz;
    for(int k = 0; k < 4; ++k){
        int i = tid + k*1024;
        p[i] = zi[k] + beta * pi[k];
    }
    if(tid == 0){ wf[1] = rznew; wf[0] = 0.f; }
}

// ---------------- SVT: register-resident one-sided Jacobi, Brent-Luk circle ----------------
// 32 groups x 4 lanes (128 thr, 2 waves). Each group holds 2 columns (16 floats/lane)
// in VGPRs; per round only migrating columns go through padded LDS mailboxes.
// Column order/sign is irrelevant: Ltmp = W diag((s-thr)_+/s^3) (W^T X).
#define P_MA(par) (POOL + (par)*2176)          // 32 slots x MCS
#define P_MB(par) (POOL + 4352 + (par)*2176)
#define P_XSH     (POOL + 8704)                // 4096 floats
#define P_TSH     (POOL)                       // alias MA (post-sweep)
#define P_WC      (POOL + 4352)                // alias MB (post-sweep), 64*MCS = 4352
#define DOT4(u,v) ((u).x*(v).x + (u).y*(v).y + (u).z*(v).z + (u).w*(v).w)

__launch_bounds__(128)
__global__ void k_svt(const float* __restrict__ thP, const float* __restrict__ vp,
                      const float* __restrict__ netap,
                      const float* __restrict__ wf, float* __restrict__ out){
    __shared__ float POOL[12800];
    __shared__ float s2[64], coef3[64];
    __shared__ float smax_sh;
    int tid = threadIdx.x;
    const float* x = wf + OFF_X;
    float* Xsh = P_XSH;

    for(int k = 0; k < 32; ++k){
        int n = tid + k*128;
        Xsh[n] = x[n] + thP[n];
    }
    __syncthreads();

    int g  = tid >> 2;      // group 0..31
    int sl = tid & 3;       // sub-lane: rows sl*16 .. sl*16+15
    // load initial columns a=2g, b=2g+1 into registers
    float4 A0,A1,A2,A3, B0,B1,B2,B3;
    {
        int ca = 2*g, cb = 2*g + 1, r0 = sl*16;
        #define LDCOL(V,C,RO) V.x = Xsh[(r0+RO+0)*64+(C)]; V.y = Xsh[(r0+RO+1)*64+(C)]; \
                              V.z = Xsh[(r0+RO+2)*64+(C)]; V.w = Xsh[(r0+RO+3)*64+(C)];
        LDCOL(A0,ca,0) LDCOL(A1,ca,4) LDCOL(A2,ca,8) LDCOL(A3,ca,12)
        LDCOL(B0,cb,0) LDCOL(B1,cb,4) LDCOL(B2,cb,8) LDCOL(B3,cb,12)
        #undef LDCOL
    }

    const int total = NSWEEP * 63;
    float aa = 0.f, bb = 0.f;
    for(int gr = 0; gr < total; ++gr){
        aa = DOT4(A0,A0)+DOT4(A1,A1)+DOT4(A2,A2)+DOT4(A3,A3);
        bb = DOT4(B0,B0)+DOT4(B1,B1)+DOT4(B2,B2)+DOT4(B3,B3);
        float cc = DOT4(A0,B0)+DOT4(A1,B1)+DOT4(A2,B2)+DOT4(A3,B3);
        aa += __shfl_xor(aa, 1); bb += __shfl_xor(bb, 1); cc += __shfl_xor(cc, 1);
        aa += __shfl_xor(aa, 2); bb += __shfl_xor(bb, 2); cc += __shfl_xor(cc, 2);
        if(fabsf(cc) > 1e-30f){
            float zeta = (bb - aa) / (2.f * cc);
            float t = copysignf(1.f / (fabsf(zeta) + sqrtf(1.f + zeta*zeta)), zeta);
            float cs = rsqrtf(1.f + t*t);
            float sn = t * cs;
            float4 na;
            #define ROT(Aq,Bq) na.x = cs*Aq.x - sn*Bq.x; na.y = cs*Aq.y - sn*Bq.y; \
                               na.z = cs*Aq.z - sn*Bq.z; na.w = cs*Aq.w - sn*Bq.w; \
                               Bq.x = sn*Aq.x + cs*Bq.x; Bq.y = sn*Aq.y + cs*Bq.y; \
                               Bq.z = sn*Aq.z + cs*Bq.z; Bq.w = sn*Aq.w + cs*Bq.w; Aq = na;
            ROT(A0,B0) ROT(A1,B1) ROT(A2,B2) ROT(A3,B3)
            #undef ROT
        }
        if(gr != total - 1){
            int par = gr & 1;
            float* MAp = P_MA(par);
            float* MBp = P_MB(par);
            // write B: g==0 -> MA slot 1 ; else MB slot g-1
            float* wb = (g == 0) ? (MAp + 1*MCS + sl*16) : (MBp + (g-1)*MCS + sl*16);
            *(float4*)(wb)      = B0;  *(float4*)(wb + 4)  = B1;
            *(float4*)(wb + 8)  = B2;  *(float4*)(wb + 12) = B3;
            // write A: groups 1..30 -> MA slot g+1
            if(g >= 1 && g <= 30){
                float* wa = MAp + (g+1)*MCS + sl*16;
                *(float4*)(wa)      = A0;  *(float4*)(wa + 4)  = A1;
                *(float4*)(wa + 8)  = A2;  *(float4*)(wa + 12) = A3;
            }
            __syncthreads();
            float4 nA0=A0, nA1=A1, nA2=A2, nA3=A3;   // g==0 keeps A
            float4 nB0=A0, nB1=A1, nB2=A2, nB3=A3;   // g==31: new B = old A
            if(g >= 1){
                const float* ra = MAp + g*MCS + sl*16;
                nA0 = *(const float4*)(ra);      nA1 = *(const float4*)(ra + 4);
                nA2 = *(const float4*)(ra + 8);  nA3 = *(const float4*)(ra + 12);
            }
            if(g <= 30){
                const float* rb = MBp + g*MCS + sl*16;
                nB0 = *(const float4*)(rb);      nB1 = *(const float4*)(rb + 4);
                nB2 = *(const float4*)(rb + 8);  nB3 = *(const float4*)(rb + 12);
            }
            A0=nA0; A1=nA1; A2=nA2; A3=nA3;
            B0=nB0; B1=nB1; B2=nB2; B3=nB3;
        }
    }
    // final column norms from registers (aa,bb hold final dots pre-rotation; recompute post-rotation)
    {
        float fa = DOT4(A0,A0)+DOT4(A1,A1)+DOT4(A2,A2)+DOT4(A3,A3);
        float fb = DOT4(B0,B0)+DOT4(B1,B1)+DOT4(B2,B2)+DOT4(B3,B3);
        fa += __shfl_xor(fa, 1); fb += __shfl_xor(fb, 1);
        fa += __shfl_xor(fa, 2); fb += __shfl_xor(fb, 2);
        __syncthreads();   // all mailbox reads done before Wc (aliases MB) is written
        float* Wc = P_WC;
        float* wa = Wc + (2*g)*MCS + sl*16;
        *(float4*)(wa)      = A0;  *(float4*)(wa + 4)  = A1;
        *(float4*)(wa + 8)  = A2;  *(float4*)(wa + 12) = A3;
        float* wb = Wc + (2*g+1)*MCS + sl*16;
        *(float4*)(wb)      = B0;  *(float4*)(wb + 4)  = B1;
        *(float4*)(wb + 8)  = B2;  *(float4*)(wb + 12) = B3;
        if(sl == 0){ s2[2*g] = fa; s2[2*g+1] = fb; }
    }
    __syncthreads();
    if(tid == 0){
        float sm = 0.f;
        for(int c = 0; c < 64; ++c) sm = fmaxf(sm, s2[c]);
        smax_sh = sqrtf(sm);
    }
    __syncthreads();
    if(tid < 64){
        float s = sqrtf(s2[tid]);
        float v = vp[0];
        float tau = 0.4f / (1.f + expf(-v));     // sigmoid(v)*COEF_GAMMA
        float thr = tau * smax_sh;
        coef3[tid] = (s > thr && s > 1e-20f) ? (s - thr) / (s*s*s) : 0.f;
    }
    __syncthreads();

    const float* Wc = P_WC;
    float* Tsh = P_TSH;
    // R1: T'[k][j] = coef3[k] * sum_r Wc[k][r] * Xsh[r][j]   (128 threads, 2 halves)
    for(int half = 0; half < 2; ++half){
        int kk = tid >> 1;
        int j0 = (tid & 1) * 32 + half * 16;
        float acc[16];
        #pragma unroll
        for(int j = 0; j < 16; ++j) acc[j] = 0.f;
        for(int r = 0; r < 64; ++r){
            float wk = Wc[kk*MCS + r];
            const float* xr = Xsh + r*64 + j0;
            float4 x0 = *(const float4*)(xr);
            float4 x1 = *(const float4*)(xr + 4);
            float4 x2 = *(const float4*)(xr + 8);
            float4 x3 = *(const float4*)(xr + 12);
            acc[0]+=wk*x0.x; acc[1]+=wk*x0.y; acc[2]+=wk*x0.z; acc[3]+=wk*x0.w;
            acc[4]+=wk*x1.x; acc[5]+=wk*x1.y; acc[6]+=wk*x1.z; acc[7]+=wk*x1.w;
            acc[8]+=wk*x2.x; acc[9]+=wk*x2.y; acc[10]+=wk*x2.z; acc[11]+=wk*x2.w;
            acc[12]+=wk*x3.x; acc[13]+=wk*x3.y; acc[14]+=wk*x3.z; acc[15]+=wk*x3.w;
        }
        float c3 = coef3[kk];
        float* tr = Tsh + kk*64 + j0;
        #pragma unroll
        for(int j = 0; j < 16; ++j) tr[j] = c3 * acc[j];
    }
    __syncthreads();

    // R2: Ltmp[i][j] = sum_k Wc[k][i] * T'[k][j]; outputs
    float neta = netap[0];
    for(int half = 0; half < 2; ++half){
        int i  = tid >> 1;
        int j0 = (tid & 1) * 32 + half * 16;
        float acc[16];
        #pragma unroll
        for(int j = 0; j < 16; ++j) acc[j] = 0.f;
        for(int kk = 0; kk < 64; ++kk){
            float wik = Wc[kk*MCS + i];
            const float* tr = Tsh + kk*64 + j0;
            float4 t0 = *(const float4*)(tr);
            float4 t1 = *(const float4*)(tr + 4);
            float4 t2 = *(const float4*)(tr + 8);
            float4 t3 = *(const float4*)(tr + 12);
            acc[0]+=wik*t0.x; acc[1]+=wik*t0.y; acc[2]+=wik*t0.z; acc[3]+=wik*t0.w;
            acc[4]+=wik*t1.x; acc[5]+=wik*t1.y; acc[6]+=wik*t1.z; acc[7]+=wik*t1.w;
            acc[8]+=wik*t2.x; acc[9]+=wik*t2.y; acc[10]+=wik*t2.z; acc[11]+=wik*t2.w;
            acc[12]+=wik*t3.x; acc[13]+=wik*t3.y; acc[14]+=wik*t3.z; acc[15]+=wik*t3.w;
        }
        int n0 = i*64 + j0;
        #pragma unroll
        for(int c = 0; c < 4; ++c){
            float4 th = *(const float4*)(thP + n0 + 4*c);
            float4 lt, pt;
            lt.x = acc[4*c+0]; lt.y = acc[4*c+1]; lt.z = acc[4*c+2]; lt.w = acc[4*c+3];
            float4 xs = *(const float4*)(Xsh + n0 + 4*c);
            pt.x = th.x + neta * (xs.x - th.x - lt.x);
            pt.y = th.y + neta * (xs.y - th.y - lt.y);
            pt.z = th.z + neta * (xs.z - th.z - lt.z);
            pt.w = th.w + neta * (xs.w - th.w - lt.w);
            *(float4*)(out + n0 + 4*c)      = lt;
            *(float4*)(out + NN + n0 + 4*c) = pt;
        }
    }
}

extern "C" void kernel_launch(void* const* d_in, const int* in_sizes, int n_in,
                              void* d_out, int out_size, void* d_ws, size_t ws_size,
                              hipStream_t stream){
    const float* inp  = (const float*)d_in[0];
    const float* L    = (const float*)d_in[1];
    const int*   mask = (const int*)  d_in[2];
    const float* D    = (const float*)d_in[3];
    const float* thP  = (const float*)d_in[4];
    const float* vS   = (const float*)d_in[5];
    const float* neta = (const float*)d_in[6];
    const float* l1   = (const float*)d_in[7];
    const float* l2   = (const float*)d_in[8];
    const float* rho  = (const float*)d_in[9];
    const float* S    = (const float*)d_in[10];
    float* wf = (float*)d_ws;
    float* out = (float*)d_out;
    const bool use_bf16 = (ws_size >= WS_NEED_BF16);
    unsigned short* Dh = (unsigned short*)((char*)d_ws + DH_OFF_BYTES);

    hipMemsetAsync(d_ws, 0, 64 * sizeof(float), stream);
    k_prep<<<16, 256, 0, stream>>>(inp, L, mask, thP, S, l2, rho, wf);
    if(use_bf16){
        k_matvec_fc<<<1024, 256, 0, stream>>>(D, Dh, l1, l2, wf);
        k_cgupd<<<1, 1024, 0, stream>>>(wf);
        for(int it = 1; it < NITER; ++it){
            k_matvec_h<<<1024, 256, 0, stream>>>(Dh, l1, l2, wf);
            k_cgupd  <<<1, 1024, 0, stream>>>(wf);
        }
    } else {
        for(int it = 0; it < NITER; ++it){
            k_matvec_f<<<1024, 256, 0, stream>>>(D, l1, l2, wf);
            k_cgupd  <<<1, 1024, 0, stream>>>(wf);
        }
    }
    k_svt<<<1, 128, 0, stream>>>(thP, vS, neta, wf, out);
}

// Round 8
// 425.412 us; speedup vs baseline: 2.2710x; 1.1289x over previous
//
#include <hip/hip_runtime.h>
#include <hip/hip_bf16.h>

#define NN 4096
#define NITER 5
#define NSWEEP 5
#define MCS 68     // mailbox/Wc column stride (floats)

// workspace float layout (double-buffered CG vectors INCLUDING y)
#define OFF_STS  64
#define OFF_QRHO (OFF_STS + NN)
#define OFF_DINV (OFF_QRHO + NN)
#define OFF_Y0   (OFF_DINV + NN)
#define OFF_Y1   (OFF_Y0 + NN)
#define OFF_X0   (OFF_Y1 + NN)
#define OFF_X1   (OFF_X0 + NN)
#define OFF_R0   (OFF_X1 + NN)
#define OFF_R1   (OFF_R0 + NN)
#define OFF_P0   (OFF_R1 + NN)
#define OFF_P1   (OFF_P0 + NN)
// wf[8+j] = pTy accumulator for CG iteration j (zeroed by memset)
#define DH_OFF_BYTES 196608
#define WS_NEED_BF16 (DH_OFF_BYTES + (size_t)NN * NN * 2)

typedef unsigned int uint;
__device__ inline float lo2f(uint w){ return __uint_as_float(w << 16); }
__device__ inline float hi2f(uint w){ return __uint_as_float(w & 0xffff0000u); }
__device__ inline uint f2b(float f){
    uint u = __float_as_uint(f);
    return (u + 0x7FFFu + ((u >> 16) & 1u)) >> 16;   // RNE
}

// ---------------- prep: StS + b + approx diag + CG init ----------------
__global__ void k_prep(const float* __restrict__ inp, const float* __restrict__ L,
                       const int*  __restrict__ mask, const float* __restrict__ thP,
                       const float* __restrict__ S,
                       const float* __restrict__ l2p, const float* __restrict__ rhop,
                       float* __restrict__ wf){
    int t = blockIdx.x * 256 + threadIdx.x;   // 4096 threads
    int r = t >> 6, c = t & 63;
    float acc = 0.f, acc2 = 0.f;
    for(int h = 0; h < 64; ++h){
        float sr = S[h*64 + r];
        float sc = S[h*64 + c];
        acc  += sr * sc;
        acc2 += sc * sc;
    }
    wf[OFF_STS + t] = acc;
    float rho = rhop[0], l2 = l2p[0];
    float q = (mask[t] != 0) ? 1.f : 0.f;
    float bi = rho * (L[t] - thP[t]) + q * inp[t];
    float dinv = 1.f / (q + rho + l2 * acc2);   // preconditioner only
    wf[OFF_QRHO + t] = q + rho;
    wf[OFF_DINV + t] = dinv;
    wf[OFF_X0 + t]   = 0.f;
    wf[OFF_R0 + t]   = bi;
    wf[OFF_P0 + t]   = bi * dinv;
}

// ---------------- per-block redundant CG scalar update (no fences needed) ----------------
// Reads PREVIOUS kernel's rold/pold/xold/yold + pTy slot; all blocks compute the
// identical update; block 0 persists r_j, p_j, x_j to the other buffer.
__device__ inline void cg_prologue(float* __restrict__ wf,
                                   const float* __restrict__ rold, const float* __restrict__ pold,
                                   const float* __restrict__ xold, const float* __restrict__ yold,
                                   float* __restrict__ rnew, float* __restrict__ pnew,
                                   float* __restrict__ xnew,
                                   int slot_old, float* __restrict__ psh,
                                   float* __restrict__ red){
    int tid = threadIdx.x;
    const float* dinv = wf + OFF_DINV;
    float4 r4[4], d4[4];
    float part = 0.f;
    #pragma unroll
    for(int k = 0; k < 4; ++k){
        r4[k] = ((const float4*)rold)[tid + k*256];
        d4[k] = ((const float4*)dinv)[tid + k*256];
        part += r4[k].x*r4[k].x*d4[k].x + r4[k].y*r4[k].y*d4[k].y
              + r4[k].z*r4[k].z*d4[k].z + r4[k].w*r4[k].w*d4[k].w;
    }
    for(int m = 32; m >= 1; m >>= 1) part += __shfl_xor(part, m, 64);
    int wave = tid >> 6, lane = tid & 63;
    if(lane == 0) red[wave] = part;
    __syncthreads();
    float rzold = red[0] + red[1] + red[2] + red[3];
    float alpha = rzold / wf[slot_old];
    float4 rn[4], zn[4];
    float part2 = 0.f;
    #pragma unroll
    for(int k = 0; k < 4; ++k){
        float4 y4 = ((const float4*)yold)[tid + k*256];
        rn[k].x = r4[k].x - alpha*y4.x;  rn[k].y = r4[k].y - alpha*y4.y;
        rn[k].z = r4[k].z - alpha*y4.z;  rn[k].w = r4[k].w - alpha*y4.w;
        zn[k].x = rn[k].x*d4[k].x;  zn[k].y = rn[k].y*d4[k].y;
        zn[k].z = rn[k].z*d4[k].z;  zn[k].w = rn[k].w*d4[k].w;
        part2 += rn[k].x*zn[k].x + rn[k].y*zn[k].y + rn[k].z*zn[k].z + rn[k].w*zn[k].w;
    }
    for(int m = 32; m >= 1; m >>= 1) part2 += __shfl_xor(part2, m, 64);
    __syncthreads();                      // all reads of red done
    if(lane == 0) red[wave] = part2;
    __syncthreads();
    float rznew = red[0] + red[1] + red[2] + red[3];
    float beta = rznew / rzold;
    bool b0 = (blockIdx.x == 0);
    #pragma unroll
    for(int k = 0; k < 4; ++k){
        float4 po = ((const float4*)pold)[tid + k*256];
        float4 pn;
        pn.x = zn[k].x + beta*po.x;  pn.y = zn[k].y + beta*po.y;
        pn.z = zn[k].z + beta*po.z;  pn.w = zn[k].w + beta*po.w;
        ((float4*)psh)[tid + k*256] = pn;
        if(b0){
            ((float4*)pnew)[tid + k*256] = pn;
            ((float4*)rnew)[tid + k*256] = rn[k];
            float4 xo = ((const float4*)xold)[tid + k*256];
            float4 xn;
            xn.x = xo.x + alpha*po.x;  xn.y = xo.y + alpha*po.y;
            xn.z = xo.z + alpha*po.z;  xn.w = xo.w + alpha*po.w;
            ((float4*)xnew)[tid + k*256] = xn;
        }
    }
    __syncthreads();
}

// ---------------- CG step j>=1: prologue + y = A p (bf16 D) + pTy ----------------
__launch_bounds__(256)
__global__ void k_step_h(const unsigned short* __restrict__ Dh,
                         const float* __restrict__ l1p, const float* __restrict__ l2p,
                         float* __restrict__ wf,
                         const float* __restrict__ rold, const float* __restrict__ pold,
                         const float* __restrict__ xold, const float* __restrict__ yold,
                         float* __restrict__ rnew, float* __restrict__ pnew,
                         float* __restrict__ xnew, float* __restrict__ ynew,
                         int slot_old, int slot_new){
    __shared__ float psh[NN];
    __shared__ float red[4];
    int tid = threadIdx.x;
    cg_prologue(wf, rold, pold, xold, yold, rnew, pnew, xnew, slot_old, psh, red);

    float l1 = l1p[0], l2 = l2p[0];
    int wave = tid >> 6, lane = tid & 63;
    int row = blockIdx.x * 4 + wave;
    int h = row >> 6, u = row & 63;
    const float* qrho = wf + OFF_QRHO;
    const float* StS  = wf + OFF_STS;

    const unsigned short* Drow = Dh + (size_t)row * NN;
    float dacc = 0.f;
    for(int j = 0; j < 8; ++j){
        int c0 = j*512 + lane*8;
        uint4 dv = *(const uint4*)(Drow + c0);
        float4 pa = *(const float4*)(psh + c0);
        float4 pb = *(const float4*)(psh + c0 + 4);
        dacc += lo2f(dv.x)*pa.x + hi2f(dv.x)*pa.y
              + lo2f(dv.y)*pa.z + hi2f(dv.y)*pa.w
              + lo2f(dv.z)*pb.x + hi2f(dv.z)*pb.y
              + lo2f(dv.w)*pb.z + hi2f(dv.w)*pb.w;
    }
    float sacc = StS[u*64 + lane] * psh[h*64 + lane];
    float val = l1 * dacc + l2 * sacc;
    for(int m = 32; m >= 1; m >>= 1) val += __shfl_xor(val, m, 64);
    if(lane == 0){
        float yi = val + qrho[row] * psh[row];
        ynew[row] = yi;
        red[wave] = yi * psh[row];
    }
    __syncthreads();
    if(tid == 0) atomicAdd(&wf[slot_new], red[0] + red[1] + red[2] + red[3]);
}

// ---------------- CG step 0: fp32 D matvec + emit bf16 Dh (no prologue) ----------------
__launch_bounds__(256)
__global__ void k_step_fc(const float* __restrict__ D, unsigned short* __restrict__ Dh,
                          const float* __restrict__ l1p, const float* __restrict__ l2p,
                          float* __restrict__ wf, const float* __restrict__ p0,
                          float* __restrict__ ynew, int slot_new){
    __shared__ float psh[NN];
    __shared__ float red[4];
    int tid = threadIdx.x;
    for(int k = 0; k < 4; ++k)
        ((float4*)psh)[tid + k*256] = ((const float4*)p0)[tid + k*256];
    __syncthreads();

    float l1 = l1p[0], l2 = l2p[0];
    int wave = tid >> 6, lane = tid & 63;
    int row = blockIdx.x * 4 + wave;
    int h = row >> 6, u = row & 63;
    const float* qrho = wf + OFF_QRHO;
    const float* StS  = wf + OFF_STS;

    const float* Drow = D + (size_t)row * NN;
    unsigned short* Dhrow = Dh + (size_t)row * NN;
    float dacc = 0.f;
    for(int j = 0; j < 16; ++j){
        int c0 = j*256 + lane*4;
        float4 dv = *(const float4*)(Drow + c0);
        float4 pa = *(const float4*)(psh + c0);
        dacc += dv.x*pa.x + dv.y*pa.y + dv.z*pa.z + dv.w*pa.w;
        uint2 o;
        o.x = f2b(dv.x) | (f2b(dv.y) << 16);
        o.y = f2b(dv.z) | (f2b(dv.w) << 16);
        *(uint2*)(Dhrow + c0) = o;
    }
    float sacc = StS[u*64 + lane] * psh[h*64 + lane];
    float val = l1 * dacc + l2 * sacc;
    for(int m = 32; m >= 1; m >>= 1) val += __shfl_xor(val, m, 64);
    if(lane == 0){
        float yi = val + qrho[row] * psh[row];
        ynew[row] = yi;
        red[wave] = yi * psh[row];
    }
    __syncthreads();
    if(tid == 0) atomicAdd(&wf[slot_new], red[0] + red[1] + red[2] + red[3]);
}

// ---------------- CG step fp32 fallback (do_pro selects prologue) ----------------
__launch_bounds__(256)
__global__ void k_step_f(const float* __restrict__ D,
                         const float* __restrict__ l1p, const float* __restrict__ l2p,
                         float* __restrict__ wf,
                         const float* __restrict__ rold, const float* __restrict__ pold,
                         const float* __restrict__ xold, const float* __restrict__ yold,
                         float* __restrict__ rnew, float* __restrict__ pnew,
                         float* __restrict__ xnew, float* __restrict__ ynew,
                         int slot_old, int slot_new, int do_pro){
    __shared__ float psh[NN];
    __shared__ float red[4];
    int tid = threadIdx.x;
    if(do_pro){
        cg_prologue(wf, rold, pold, xold, yold, rnew, pnew, xnew, slot_old, psh, red);
    } else {
        for(int k = 0; k < 4; ++k)
            ((float4*)psh)[tid + k*256] = ((const float4*)pold)[tid + k*256];
        __syncthreads();
    }
    float l1 = l1p[0], l2 = l2p[0];
    int wave = tid >> 6, lane = tid & 63;
    int row = blockIdx.x * 4 + wave;
    int h = row >> 6, u = row & 63;
    const float* qrho = wf + OFF_QRHO;
    const float* StS  = wf + OFF_STS;
    const float* Drow = D + (size_t)row * NN;
    float dacc = 0.f;
    for(int j = 0; j < 16; ++j){
        int c0 = j*256 + lane*4;
        float4 dv = *(const float4*)(Drow + c0);
        float4 pa = *(const float4*)(psh + c0);
        dacc += dv.x*pa.x + dv.y*pa.y + dv.z*pa.z + dv.w*pa.w;
    }
    float sacc = StS[u*64 + lane] * psh[h*64 + lane];
    float val = l1 * dacc + l2 * sacc;
    for(int m = 32; m >= 1; m >>= 1) val += __shfl_xor(val, m, 64);
    if(lane == 0){
        float yi = val + qrho[row] * psh[row];
        ynew[row] = yi;
        red[wave] = yi * psh[row];
    }
    __syncthreads();
    if(tid == 0) atomicAdd(&wf[slot_new], red[0] + red[1] + red[2] + red[3]);
}

// ---------------- SVT: register-resident Brent-Luk Jacobi + final CG update fused ----------------
#define P_MA(par) (POOL + (par)*2176)
#define P_MB(par) (POOL + 4352 + (par)*2176)
#define P_XSH     (POOL + 8704)
#define P_TSH     (POOL)
#define P_WC      (POOL + 4352)
#define DOT4(u,v) ((u).x*(v).x + (u).y*(v).y + (u).z*(v).z + (u).w*(v).w)

__launch_bounds__(128)
__global__ void k_svt(const float* __restrict__ thP, const float* __restrict__ vp,
                      const float* __restrict__ netap,
                      float* __restrict__ wf,
                      const float* __restrict__ rlast, const float* __restrict__ plast,
                      const float* __restrict__ xlast, int slot_last,
                      float* __restrict__ out){
    __shared__ float POOL[12800];
    __shared__ float s2[64], coef3[64];
    __shared__ float smax_sh;
    __shared__ float redv[2];
    int tid = threadIdx.x;
    float* Xsh = P_XSH;

    // fused final CG update: alpha_last = rz_last / pTy_last ; X = x + alpha*p + thP
    {
        const float* dinv = wf + OFF_DINV;
        float part = 0.f;
        #pragma unroll
        for(int k = 0; k < 8; ++k){
            float4 r4 = ((const float4*)rlast)[tid + k*128];
            float4 d4 = ((const float4*)dinv)[tid + k*128];
            part += r4.x*r4.x*d4.x + r4.y*r4.y*d4.y + r4.z*r4.z*d4.z + r4.w*r4.w*d4.w;
        }
        for(int m = 32; m >= 1; m >>= 1) part += __shfl_xor(part, m, 64);
        if((tid & 63) == 0) redv[tid >> 6] = part;
        __syncthreads();
        float a = (redv[0] + redv[1]) / wf[slot_last];
        #pragma unroll
        for(int k = 0; k < 8; ++k){
            float4 x4 = ((const float4*)xlast)[tid + k*128];
            float4 p4 = ((const float4*)plast)[tid + k*128];
            float4 t4 = ((const float4*)thP)[tid + k*128];
            float4 v;
            v.x = x4.x + a*p4.x + t4.x;  v.y = x4.y + a*p4.y + t4.y;
            v.z = x4.z + a*p4.z + t4.z;  v.w = x4.w + a*p4.w + t4.w;
            ((float4*)Xsh)[tid + k*128] = v;
        }
    }
    __syncthreads();

    int g  = tid >> 2;      // group 0..31
    int sl = tid & 3;       // sub-lane: rows sl*16 .. sl*16+15
    float4 A0,A1,A2,A3, B0,B1,B2,B3;
    {
        int ca = 2*g, cb = 2*g + 1, r0 = sl*16;
        #define LDCOL(V,C,RO) V.x = Xsh[(r0+RO+0)*64+(C)]; V.y = Xsh[(r0+RO+1)*64+(C)]; \
                              V.z = Xsh[(r0+RO+2)*64+(C)]; V.w = Xsh[(r0+RO+3)*64+(C)];
        LDCOL(A0,ca,0) LDCOL(A1,ca,4) LDCOL(A2,ca,8) LDCOL(A3,ca,12)
        LDCOL(B0,cb,0) LDCOL(B1,cb,4) LDCOL(B2,cb,8) LDCOL(B3,cb,12)
        #undef LDCOL
    }

    const int total = NSWEEP * 63;
    for(int gr = 0; gr < total; ++gr){
        float aa = DOT4(A0,A0)+DOT4(A1,A1)+DOT4(A2,A2)+DOT4(A3,A3);
        float bb = DOT4(B0,B0)+DOT4(B1,B1)+DOT4(B2,B2)+DOT4(B3,B3);
        float cc = DOT4(A0,B0)+DOT4(A1,B1)+DOT4(A2,B2)+DOT4(A3,B3);
        aa += __shfl_xor(aa, 1); bb += __shfl_xor(bb, 1); cc += __shfl_xor(cc, 1);
        aa += __shfl_xor(aa, 2); bb += __shfl_xor(bb, 2); cc += __shfl_xor(cc, 2);
        float cs = 1.f, sn = 0.f;
        if(fabsf(cc) > 1e-30f){
            // fast-approx angle (Jacobi is self-correcting)
            float zeta = (bb - aa) * 0.5f * __builtin_amdgcn_rcpf(cc);
            float t = copysignf(__builtin_amdgcn_rcpf(fabsf(zeta) +
                          __builtin_amdgcn_sqrtf(1.f + zeta*zeta)), zeta);
            cs = __builtin_amdgcn_rsqf(1.f + t*t);
            sn = t * cs;
        }
        if(gr != total - 1){
            int par = gr & 1;
            float* MAp = P_MA(par);
            float* MBp = P_MB(par);
            // rotate & ship outgoing B first (overlap write latency with A rotation)
            float4 nb0, nb1, nb2, nb3;
            nb0.x = sn*A0.x + cs*B0.x; nb0.y = sn*A0.y + cs*B0.y;
            nb0.z = sn*A0.z + cs*B0.z; nb0.w = sn*A0.w + cs*B0.w;
            nb1.x = sn*A1.x + cs*B1.x; nb1.y = sn*A1.y + cs*B1.y;
            nb1.z = sn*A1.z + cs*B1.z; nb1.w = sn*A1.w + cs*B1.w;
            nb2.x = sn*A2.x + cs*B2.x; nb2.y = sn*A2.y + cs*B2.y;
            nb2.z = sn*A2.z + cs*B2.z; nb2.w = sn*A2.w + cs*B2.w;
            nb3.x = sn*A3.x + cs*B3.x; nb3.y = sn*A3.y + cs*B3.y;
            nb3.z = sn*A3.z + cs*B3.z; nb3.w = sn*A3.w + cs*B3.w;
            float* wb = (g == 0) ? (MAp + 1*MCS + sl*16) : (MBp + (g-1)*MCS + sl*16);
            *(float4*)(wb)      = nb0;  *(float4*)(wb + 4)  = nb1;
            *(float4*)(wb + 8)  = nb2;  *(float4*)(wb + 12) = nb3;
            float4 na0, na1, na2, na3;
            na0.x = cs*A0.x - sn*B0.x; na0.y = cs*A0.y - sn*B0.y;
            na0.z = cs*A0.z - sn*B0.z; na0.w = cs*A0.w - sn*B0.w;
            na1.x = cs*A1.x - sn*B1.x; na1.y = cs*A1.y - sn*B1.y;
            na1.z = cs*A1.z - sn*B1.z; na1.w = cs*A1.w - sn*B1.w;
            na2.x = cs*A2.x - sn*B2.x; na2.y = cs*A2.y - sn*B2.y;
            na2.z = cs*A2.z - sn*B2.z; na2.w = cs*A2.w - sn*B2.w;
            na3.x = cs*A3.x - sn*B3.x; na3.y = cs*A3.y - sn*B3.y;
            na3.z = cs*A3.z - sn*B3.z; na3.w = cs*A3.w - sn*B3.w;
            if(g >= 1 && g <= 30){
                float* wa = MAp + (g+1)*MCS + sl*16;
                *(float4*)(wa)      = na0;  *(float4*)(wa + 4)  = na1;
                *(float4*)(wa + 8)  = na2;  *(float4*)(wa + 12) = na3;
            }
            __syncthreads();
            float4 nA0=na0, nA1=na1, nA2=na2, nA3=na3;   // g==0 keeps rotated A
            float4 nB0=na0, nB1=na1, nB2=na2, nB3=na3;   // g==31: new B = rotated A
            if(g >= 1){
                const float* ra = MAp + g*MCS + sl*16;
                nA0 = *(const float4*)(ra);      nA1 = *(const float4*)(ra + 4);
                nA2 = *(const float4*)(ra + 8);  nA3 = *(const float4*)(ra + 12);
            }
            if(g <= 30){
                const float* rb = MBp + g*MCS + sl*16;
                nB0 = *(const float4*)(rb);      nB1 = *(const float4*)(rb + 4);
                nB2 = *(const float4*)(rb + 8);  nB3 = *(const float4*)(rb + 12);
            }
            A0=nA0; A1=nA1; A2=nA2; A3=nA3;
            B0=nB0; B1=nB1; B2=nB2; B3=nB3;
        } else {
            float4 na;
            #define ROT(Aq,Bq) na.x = cs*Aq.x - sn*Bq.x; na.y = cs*Aq.y - sn*Bq.y; \
                               na.z = cs*Aq.z - sn*Bq.z; na.w = cs*Aq.w - sn*Bq.w; \
                               Bq.x = sn*Aq.x + cs*Bq.x; Bq.y = sn*Aq.y + cs*Bq.y; \
                               Bq.z = sn*Aq.z + cs*Bq.z; Bq.w = sn*Aq.w + cs*Bq.w; Aq = na;
            ROT(A0,B0) ROT(A1,B1) ROT(A2,B2) ROT(A3,B3)
            #undef ROT
        }
    }
    // final column norms + store W to LDS
    {
        float fa = DOT4(A0,A0)+DOT4(A1,A1)+DOT4(A2,A2)+DOT4(A3,A3);
        float fb = DOT4(B0,B0)+DOT4(B1,B1)+DOT4(B2,B2)+DOT4(B3,B3);
        fa += __shfl_xor(fa, 1); fb += __shfl_xor(fb, 1);
        fa += __shfl_xor(fa, 2); fb += __shfl_xor(fb, 2);
        __syncthreads();   // mailbox reads done before Wc (aliases MB) written
        float* Wc = P_WC;
        float* wa = Wc + (2*g)*MCS + sl*16;
        *(float4*)(wa)      = A0;  *(float4*)(wa + 4)  = A1;
        *(float4*)(wa + 8)  = A2;  *(float4*)(wa + 12) = A3;
        float* wb = Wc + (2*g+1)*MCS + sl*16;
        *(float4*)(wb)      = B0;  *(float4*)(wb + 4)  = B1;
        *(float4*)(wb + 8)  = B2;  *(float4*)(wb + 12) = B3;
        if(sl == 0){ s2[2*g] = fa; s2[2*g+1] = fb; }
    }
    __syncthreads();
    if(tid == 0){
        float sm = 0.f;
        for(int c = 0; c < 64; ++c) sm = fmaxf(sm, s2[c]);
        smax_sh = sqrtf(sm);
    }
    __syncthreads();
    if(tid < 64){
        float s = sqrtf(s2[tid]);
        float v = vp[0];
        float tau = 0.4f / (1.f + expf(-v));     // sigmoid(v)*COEF_GAMMA
        float thr = tau * smax_sh;
        coef3[tid] = (s > thr && s > 1e-20f) ? (s - thr) / (s*s*s) : 0.f;
    }
    __syncthreads();

    const float* Wc = P_WC;
    float* Tsh = P_TSH;
    // R1: T'[k][j] = coef3[k] * sum_r Wc[k][r] * Xsh[r][j]
    for(int half = 0; half < 2; ++half){
        int kk = tid >> 1;
        int j0 = (tid & 1) * 32 + half * 16;
        float acc[16];
        #pragma unroll
        for(int j = 0; j < 16; ++j) acc[j] = 0.f;
        for(int r = 0; r < 64; ++r){
            float wk = Wc[kk*MCS + r];
            const float* xr = Xsh + r*64 + j0;
            float4 x0 = *(const float4*)(xr);
            float4 x1 = *(const float4*)(xr + 4);
            float4 x2 = *(const float4*)(xr + 8);
            float4 x3 = *(const float4*)(xr + 12);
            acc[0]+=wk*x0.x; acc[1]+=wk*x0.y; acc[2]+=wk*x0.z; acc[3]+=wk*x0.w;
            acc[4]+=wk*x1.x; acc[5]+=wk*x1.y; acc[6]+=wk*x1.z; acc[7]+=wk*x1.w;
            acc[8]+=wk*x2.x; acc[9]+=wk*x2.y; acc[10]+=wk*x2.z; acc[11]+=wk*x2.w;
            acc[12]+=wk*x3.x; acc[13]+=wk*x3.y; acc[14]+=wk*x3.z; acc[15]+=wk*x3.w;
        }
        float c3 = coef3[kk];
        float* tr = Tsh + kk*64 + j0;
        #pragma unroll
        for(int j = 0; j < 16; ++j) tr[j] = c3 * acc[j];
    }
    __syncthreads();

    // R2: Ltmp[i][j] = sum_k Wc[k][i] * T'[k][j]; outputs
    float neta = netap[0];
    for(int half = 0; half < 2; ++half){
        int i  = tid >> 1;
        int j0 = (tid & 1) * 32 + half * 16;
        float acc[16];
        #pragma unroll
        for(int j = 0; j < 16; ++j) acc[j] = 0.f;
        for(int kk = 0; kk < 64; ++kk){
            float wik = Wc[kk*MCS + i];
            const float* tr = Tsh + kk*64 + j0;
            float4 t0 = *(const float4*)(tr);
            float4 t1 = *(const float4*)(tr + 4);
            float4 t2 = *(const float4*)(tr + 8);
            float4 t3 = *(const float4*)(tr + 12);
            acc[0]+=wik*t0.x; acc[1]+=wik*t0.y; acc[2]+=wik*t0.z; acc[3]+=wik*t0.w;
            acc[4]+=wik*t1.x; acc[5]+=wik*t1.y; acc[6]+=wik*t1.z; acc[7]+=wik*t1.w;
            acc[8]+=wik*t2.x; acc[9]+=wik*t2.y; acc[10]+=wik*t2.z; acc[11]+=wik*t2.w;
            acc[12]+=wik*t3.x; acc[13]+=wik*t3.y; acc[14]+=wik*t3.z; acc[15]+=wik*t3.w;
        }
        int n0 = i*64 + j0;
        #pragma unroll
        for(int c = 0; c < 4; ++c){
            float4 th = *(const float4*)(thP + n0 + 4*c);
            float4 lt, pt;
            lt.x = acc[4*c+0]; lt.y = acc[4*c+1]; lt.z = acc[4*c+2]; lt.w = acc[4*c+3];
            float4 xs = *(const float4*)(Xsh + n0 + 4*c);
            pt.x = th.x + neta * (xs.x - th.x - lt.x);
            pt.y = th.y + neta * (xs.y - th.y - lt.y);
            pt.z = th.z + neta * (xs.z - th.z - lt.z);
            pt.w = th.w + neta * (xs.w - th.w - lt.w);
            *(float4*)(out + n0 + 4*c)      = lt;
            *(float4*)(out + NN + n0 + 4*c) = pt;
        }
    }
}

extern "C" void kernel_launch(void* const* d_in, const int* in_sizes, int n_in,
                              void* d_out, int out_size, void* d_ws, size_t ws_size,
                              hipStream_t stream){
    const float* inp  = (const float*)d_in[0];
    const float* L    = (const float*)d_in[1];
    const int*   mask = (const int*)  d_in[2];
    const float* D    = (const float*)d_in[3];
    const float* thP  = (const float*)d_in[4];
    const float* vS   = (const float*)d_in[5];
    const float* neta = (const float*)d_in[6];
    const float* l1   = (const float*)d_in[7];
    const float* l2   = (const float*)d_in[8];
    const float* rho  = (const float*)d_in[9];
    const float* S    = (const float*)d_in[10];
    float* wf = (float*)d_ws;
    float* out = (float*)d_out;
    const bool use_bf16 = (ws_size >= WS_NEED_BF16);
    unsigned short* Dh = (unsigned short*)((char*)d_ws + DH_OFF_BYTES);

    float* Xb[2] = { wf + OFF_X0, wf + OFF_X1 };
    float* Rb[2] = { wf + OFF_R0, wf + OFF_R1 };
    float* Pb[2] = { wf + OFF_P0, wf + OFF_P1 };
    float* Yb[2] = { wf + OFF_Y0, wf + OFF_Y1 };

    hipMemsetAsync(d_ws, 0, 64 * sizeof(float), stream);   // zero pTy slots
    k_prep<<<16, 256, 0, stream>>>(inp, L, mask, thP, S, l2, rho, wf);
    if(use_bf16){
        k_step_fc<<<1024, 256, 0, stream>>>(D, Dh, l1, l2, wf, Pb[0], Yb[0], 8);
        for(int j = 1; j < NITER; ++j){
            int ro = (j+1)&1, wr = j&1;
            k_step_h<<<1024, 256, 0, stream>>>(Dh, l1, l2, wf,
                Rb[ro], Pb[ro], Xb[ro], Yb[ro],
                Rb[wr], Pb[wr], Xb[wr], Yb[wr], 8+j-1, 8+j);
        }
    } else {
        k_step_f<<<1024, 256, 0, stream>>>(D, l1, l2, wf,
            Rb[0], Pb[0], Xb[0], Yb[0], Rb[1], Pb[1], Xb[1], Yb[0], 8, 8, 0);
        for(int j = 1; j < NITER; ++j){
            int ro = (j+1)&1, wr = j&1;
            k_step_f<<<1024, 256, 0, stream>>>(D, l1, l2, wf,
                Rb[ro], Pb[ro], Xb[ro], Yb[ro],
                Rb[wr], Pb[wr], Xb[wr], Yb[wr], 8+j-1, 8+j, 1);
        }
    }
    // NITER=5 odd -> last write parity = (NITER-1)&1 = 0
    k_svt<<<1, 128, 0, stream>>>(thP, vS, neta, wf, Rb[0], Pb[0], Xb[0], 8+NITER-1, out);
}

// Round 9
// 372.382 us; speedup vs baseline: 2.5945x; 1.1424x over previous
//
#include <hip/hip_runtime.h>
#include <hip/hip_bf16.h>

#define NN 4096
#define NITER 4
#define NSWEEP 5
#define MCS 68     // mailbox/Wc column stride (floats)

// workspace float layout (double-buffered CG vectors INCLUDING y)
#define OFF_STS  64
#define OFF_QRHO (OFF_STS + NN)
#define OFF_DINV (OFF_QRHO + NN)
#define OFF_Y0   (OFF_DINV + NN)
#define OFF_Y1   (OFF_Y0 + NN)
#define OFF_X0   (OFF_Y1 + NN)
#define OFF_X1   (OFF_X0 + NN)
#define OFF_R0   (OFF_X1 + NN)
#define OFF_R1   (OFF_R0 + NN)
#define OFF_P0   (OFF_R1 + NN)
#define OFF_P1   (OFF_P0 + NN)
// wf[8+j] = pTy accumulator for CG iteration j (zeroed by k_prep block 0)
#define DH_OFF_BYTES 196608
#define WS_NEED_BF16 (DH_OFF_BYTES + (size_t)NN * NN * 2)

typedef unsigned int uint;
__device__ inline float lo2f(uint w){ return __uint_as_float(w << 16); }
__device__ inline float hi2f(uint w){ return __uint_as_float(w & 0xffff0000u); }
__device__ inline uint f2b(float f){
    uint u = __float_as_uint(f);
    return (u + 0x7FFFu + ((u >> 16) & 1u)) >> 16;   // RNE
}
// quad-lane sum via DPP (VALU latency, no DS pipe): valid when the 4 lanes of
// a quad form the reduction group (here group g = lanes 4g..4g+3)
__device__ inline float qsum(float x){
    int a = __float_as_int(x);
    int b = __builtin_amdgcn_update_dpp(0, a, 0xB1, 0xF, 0xF, true);   // quad_perm(1,0,3,2) = xor 1
    float s1 = x + __int_as_float(b);
    int c = __float_as_int(s1);
    int d = __builtin_amdgcn_update_dpp(0, c, 0x4E, 0xF, 0xF, true);   // quad_perm(2,3,0,1) = xor 2
    return s1 + __int_as_float(d);
}

// ---------------- prep: StS + b + approx diag + CG init + slot zeroing ----------------
__global__ void k_prep(const float* __restrict__ inp, const float* __restrict__ L,
                       const int*  __restrict__ mask, const float* __restrict__ thP,
                       const float* __restrict__ S,
                       const float* __restrict__ l2p, const float* __restrict__ rhop,
                       float* __restrict__ wf){
    int t = blockIdx.x * 256 + threadIdx.x;   // 4096 threads
    if(blockIdx.x == 0 && threadIdx.x < 64) wf[threadIdx.x] = 0.f;   // pTy slots (replaces memset dispatch)
    int r = t >> 6, c = t & 63;
    float acc = 0.f, acc2 = 0.f;
    for(int h = 0; h < 64; ++h){
        float sr = S[h*64 + r];
        float sc = S[h*64 + c];
        acc  += sr * sc;
        acc2 += sc * sc;
    }
    wf[OFF_STS + t] = acc;
    float rho = rhop[0], l2 = l2p[0];
    float q = (mask[t] != 0) ? 1.f : 0.f;
    float bi = rho * (L[t] - thP[t]) + q * inp[t];
    float dinv = 1.f / (q + rho + l2 * acc2);   // preconditioner only
    wf[OFF_QRHO + t] = q + rho;
    wf[OFF_DINV + t] = dinv;
    wf[OFF_X0 + t]   = 0.f;
    wf[OFF_R0 + t]   = bi;
    wf[OFF_P0 + t]   = bi * dinv;
}

// ---------------- per-block redundant CG scalar update (no fences needed) ----------------
__device__ inline void cg_prologue(float* __restrict__ wf,
                                   const float* __restrict__ rold, const float* __restrict__ pold,
                                   const float* __restrict__ xold, const float* __restrict__ yold,
                                   float* __restrict__ rnew, float* __restrict__ pnew,
                                   float* __restrict__ xnew,
                                   int slot_old, float* __restrict__ psh,
                                   float* __restrict__ red){
    int tid = threadIdx.x;
    const float* dinv = wf + OFF_DINV;
    float4 r4[4], d4[4];
    float part = 0.f;
    #pragma unroll
    for(int k = 0; k < 4; ++k){
        r4[k] = ((const float4*)rold)[tid + k*256];
        d4[k] = ((const float4*)dinv)[tid + k*256];
        part += r4[k].x*r4[k].x*d4[k].x + r4[k].y*r4[k].y*d4[k].y
              + r4[k].z*r4[k].z*d4[k].z + r4[k].w*r4[k].w*d4[k].w;
    }
    for(int m = 32; m >= 1; m >>= 1) part += __shfl_xor(part, m, 64);
    int wave = tid >> 6, lane = tid & 63;
    if(lane == 0) red[wave] = part;
    __syncthreads();
    float rzold = red[0] + red[1] + red[2] + red[3];
    float alpha = rzold / wf[slot_old];
    float4 rn[4], zn[4];
    float part2 = 0.f;
    #pragma unroll
    for(int k = 0; k < 4; ++k){
        float4 y4 = ((const float4*)yold)[tid + k*256];
        rn[k].x = r4[k].x - alpha*y4.x;  rn[k].y = r4[k].y - alpha*y4.y;
        rn[k].z = r4[k].z - alpha*y4.z;  rn[k].w = r4[k].w - alpha*y4.w;
        zn[k].x = rn[k].x*d4[k].x;  zn[k].y = rn[k].y*d4[k].y;
        zn[k].z = rn[k].z*d4[k].z;  zn[k].w = rn[k].w*d4[k].w;
        part2 += rn[k].x*zn[k].x + rn[k].y*zn[k].y + rn[k].z*zn[k].z + rn[k].w*zn[k].w;
    }
    for(int m = 32; m >= 1; m >>= 1) part2 += __shfl_xor(part2, m, 64);
    __syncthreads();                      // all reads of red done
    if(lane == 0) red[wave] = part2;
    __syncthreads();
    float rznew = red[0] + red[1] + red[2] + red[3];
    float beta = rznew / rzold;
    bool b0 = (blockIdx.x == 0);
    #pragma unroll
    for(int k = 0; k < 4; ++k){
        float4 po = ((const float4*)pold)[tid + k*256];
        float4 pn;
        pn.x = zn[k].x + beta*po.x;  pn.y = zn[k].y + beta*po.y;
        pn.z = zn[k].z + beta*po.z;  pn.w = zn[k].w + beta*po.w;
        ((float4*)psh)[tid + k*256] = pn;
        if(b0){
            ((float4*)pnew)[tid + k*256] = pn;
            ((float4*)rnew)[tid + k*256] = rn[k];
            float4 xo = ((const float4*)xold)[tid + k*256];
            float4 xn;
            xn.x = xo.x + alpha*po.x;  xn.y = xo.y + alpha*po.y;
            xn.z = xo.z + alpha*po.z;  xn.w = xo.w + alpha*po.w;
            ((float4*)xnew)[tid + k*256] = xn;
        }
    }
    __syncthreads();
}

// ---------------- CG step j>=1: prologue + y = A p (bf16 D) + pTy ----------------
__launch_bounds__(256)
__global__ void k_step_h(const unsigned short* __restrict__ Dh,
                         const float* __restrict__ l1p, const float* __restrict__ l2p,
                         float* __restrict__ wf,
                         const float* __restrict__ rold, const float* __restrict__ pold,
                         const float* __restrict__ xold, const float* __restrict__ yold,
                         float* __restrict__ rnew, float* __restrict__ pnew,
                         float* __restrict__ xnew, float* __restrict__ ynew,
                         int slot_old, int slot_new){
    __shared__ float psh[NN];
    __shared__ float red[4];
    int tid = threadIdx.x;
    cg_prologue(wf, rold, pold, xold, yold, rnew, pnew, xnew, slot_old, psh, red);

    float l1 = l1p[0], l2 = l2p[0];
    int wave = tid >> 6, lane = tid & 63;
    int row = blockIdx.x * 4 + wave;
    int h = row >> 6, u = row & 63;
    const float* qrho = wf + OFF_QRHO;
    const float* StS  = wf + OFF_STS;

    const unsigned short* Drow = Dh + (size_t)row * NN;
    float dacc = 0.f;
    for(int j = 0; j < 8; ++j){
        int c0 = j*512 + lane*8;
        uint4 dv = *(const uint4*)(Drow + c0);
        float4 pa = *(const float4*)(psh + c0);
        float4 pb = *(const float4*)(psh + c0 + 4);
        dacc += lo2f(dv.x)*pa.x + hi2f(dv.x)*pa.y
              + lo2f(dv.y)*pa.z + hi2f(dv.y)*pa.w
              + lo2f(dv.z)*pb.x + hi2f(dv.z)*pb.y
              + lo2f(dv.w)*pb.z + hi2f(dv.w)*pb.w;
    }
    float sacc = StS[u*64 + lane] * psh[h*64 + lane];
    float val = l1 * dacc + l2 * sacc;
    for(int m = 32; m >= 1; m >>= 1) val += __shfl_xor(val, m, 64);
    if(lane == 0){
        float yi = val + qrho[row] * psh[row];
        ynew[row] = yi;
        red[wave] = yi * psh[row];
    }
    __syncthreads();
    if(tid == 0) atomicAdd(&wf[slot_new], red[0] + red[1] + red[2] + red[3]);
}

// ---------------- CG step 0: fp32 D matvec + emit bf16 Dh (no prologue) ----------------
__launch_bounds__(256)
__global__ void k_step_fc(const float* __restrict__ D, unsigned short* __restrict__ Dh,
                          const float* __restrict__ l1p, const float* __restrict__ l2p,
                          float* __restrict__ wf, const float* __restrict__ p0,
                          float* __restrict__ ynew, int slot_new){
    __shared__ float psh[NN];
    __shared__ float red[4];
    int tid = threadIdx.x;
    for(int k = 0; k < 4; ++k)
        ((float4*)psh)[tid + k*256] = ((const float4*)p0)[tid + k*256];
    __syncthreads();

    float l1 = l1p[0], l2 = l2p[0];
    int wave = tid >> 6, lane = tid & 63;
    int row = blockIdx.x * 4 + wave;
    int h = row >> 6, u = row & 63;
    const float* qrho = wf + OFF_QRHO;
    const float* StS  = wf + OFF_STS;

    const float* Drow = D + (size_t)row * NN;
    unsigned short* Dhrow = Dh + (size_t)row * NN;
    float dacc = 0.f;
    for(int j = 0; j < 16; ++j){
        int c0 = j*256 + lane*4;
        float4 dv = *(const float4*)(Drow + c0);
        float4 pa = *(const float4*)(psh + c0);
        dacc += dv.x*pa.x + dv.y*pa.y + dv.z*pa.z + dv.w*pa.w;
        uint2 o;
        o.x = f2b(dv.x) | (f2b(dv.y) << 16);
        o.y = f2b(dv.z) | (f2b(dv.w) << 16);
        *(uint2*)(Dhrow + c0) = o;
    }
    float sacc = StS[u*64 + lane] * psh[h*64 + lane];
    float val = l1 * dacc + l2 * sacc;
    for(int m = 32; m >= 1; m >>= 1) val += __shfl_xor(val, m, 64);
    if(lane == 0){
        float yi = val + qrho[row] * psh[row];
        ynew[row] = yi;
        red[wave] = yi * psh[row];
    }
    __syncthreads();
    if(tid == 0) atomicAdd(&wf[slot_new], red[0] + red[1] + red[2] + red[3]);
}

// ---------------- CG step fp32 fallback (do_pro selects prologue) ----------------
__launch_bounds__(256)
__global__ void k_step_f(const float* __restrict__ D,
                         const float* __restrict__ l1p, const float* __restrict__ l2p,
                         float* __restrict__ wf,
                         const float* __restrict__ rold, const float* __restrict__ pold,
                         const float* __restrict__ xold, const float* __restrict__ yold,
                         float* __restrict__ rnew, float* __restrict__ pnew,
                         float* __restrict__ xnew, float* __restrict__ ynew,
                         int slot_old, int slot_new, int do_pro){
    __shared__ float psh[NN];
    __shared__ float red[4];
    int tid = threadIdx.x;
    if(do_pro){
        cg_prologue(wf, rold, pold, xold, yold, rnew, pnew, xnew, slot_old, psh, red);
    } else {
        for(int k = 0; k < 4; ++k)
            ((float4*)psh)[tid + k*256] = ((const float4*)pold)[tid + k*256];
        __syncthreads();
    }
    float l1 = l1p[0], l2 = l2p[0];
    int wave = tid >> 6, lane = tid & 63;
    int row = blockIdx.x * 4 + wave;
    int h = row >> 6, u = row & 63;
    const float* qrho = wf + OFF_QRHO;
    const float* StS  = wf + OFF_STS;
    const float* Drow = D + (size_t)row * NN;
    float dacc = 0.f;
    for(int j = 0; j < 16; ++j){
        int c0 = j*256 + lane*4;
        float4 dv = *(const float4*)(Drow + c0);
        float4 pa = *(const float4*)(psh + c0);
        dacc += dv.x*pa.x + dv.y*pa.y + dv.z*pa.z + dv.w*pa.w;
    }
    float sacc = StS[u*64 + lane] * psh[h*64 + lane];
    float val = l1 * dacc + l2 * sacc;
    for(int m = 32; m >= 1; m >>= 1) val += __shfl_xor(val, m, 64);
    if(lane == 0){
        float yi = val + qrho[row] * psh[row];
        ynew[row] = yi;
        red[wave] = yi * psh[row];
    }
    __syncthreads();
    if(tid == 0) atomicAdd(&wf[slot_new], red[0] + red[1] + red[2] + red[3]);
}

// ---------------- SVT: register-resident Brent-Luk Jacobi + final CG update fused ----------------
#define P_MA(par) (POOL + (par)*2176)
#define P_MB(par) (POOL + 4352 + (par)*2176)
#define P_XSH     (POOL + 8704)
#define P_TSH     (POOL)
#define P_WC      (POOL + 4352)
#define DOT4(u,v) ((u).x*(v).x + (u).y*(v).y + (u).z*(v).z + (u).w*(v).w)

__launch_bounds__(128)
__global__ void k_svt(const float* __restrict__ thP, const float* __restrict__ vp,
                      const float* __restrict__ netap,
                      float* __restrict__ wf,
                      const float* __restrict__ rlast, const float* __restrict__ plast,
                      const float* __restrict__ xlast, int slot_last,
                      float* __restrict__ out){
    __shared__ float POOL[12800];
    __shared__ float s2[64], coef3[64];
    __shared__ float smax_sh;
    __shared__ float redv[2];
    int tid = threadIdx.x;
    float* Xsh = P_XSH;

    // fused final CG update: alpha_last = rz_last / pTy_last ; X = x + alpha*p + thP
    {
        const float* dinv = wf + OFF_DINV;
        float part = 0.f;
        #pragma unroll
        for(int k = 0; k < 8; ++k){
            float4 r4 = ((const float4*)rlast)[tid + k*128];
            float4 d4 = ((const float4*)dinv)[tid + k*128];
            part += r4.x*r4.x*d4.x + r4.y*r4.y*d4.y + r4.z*r4.z*d4.z + r4.w*r4.w*d4.w;
        }
        for(int m = 32; m >= 1; m >>= 1) part += __shfl_xor(part, m, 64);
        if((tid & 63) == 0) redv[tid >> 6] = part;
        __syncthreads();
        float a = (redv[0] + redv[1]) / wf[slot_last];
        #pragma unroll
        for(int k = 0; k < 8; ++k){
            float4 x4 = ((const float4*)xlast)[tid + k*128];
            float4 p4 = ((const float4*)plast)[tid + k*128];
            float4 t4 = ((const float4*)thP)[tid + k*128];
            float4 v;
            v.x = x4.x + a*p4.x + t4.x;  v.y = x4.y + a*p4.y + t4.y;
            v.z = x4.z + a*p4.z + t4.z;  v.w = x4.w + a*p4.w + t4.w;
            ((float4*)Xsh)[tid + k*128] = v;
        }
    }
    __syncthreads();

    int g  = tid >> 2;      // group 0..31 (one quad of lanes)
    int sl = tid & 3;       // sub-lane: rows sl*16 .. sl*16+15
    float4 A0,A1,A2,A3, B0,B1,B2,B3;
    {
        int ca = 2*g, cb = 2*g + 1, r0 = sl*16;
        #define LDCOL(V,C,RO) V.x = Xsh[(r0+RO+0)*64+(C)]; V.y = Xsh[(r0+RO+1)*64+(C)]; \
                              V.z = Xsh[(r0+RO+2)*64+(C)]; V.w = Xsh[(r0+RO+3)*64+(C)];
        LDCOL(A0,ca,0) LDCOL(A1,ca,4) LDCOL(A2,ca,8) LDCOL(A3,ca,12)
        LDCOL(B0,cb,0) LDCOL(B1,cb,4) LDCOL(B2,cb,8) LDCOL(B3,cb,12)
        #undef LDCOL
    }

    const int total = NSWEEP * 63;
    for(int gr = 0; gr < total; ++gr){
        // quad-local reductions via DPP (VALU latency, off the DS pipe)
        float aa = qsum(DOT4(A0,A0)+DOT4(A1,A1)+DOT4(A2,A2)+DOT4(A3,A3));
        float bb = qsum(DOT4(B0,B0)+DOT4(B1,B1)+DOT4(B2,B2)+DOT4(B3,B3));
        float cc = qsum(DOT4(A0,B0)+DOT4(A1,B1)+DOT4(A2,B2)+DOT4(A3,B3));
        float cs = 1.f, sn = 0.f;
        if(fabsf(cc) > 1e-30f){
            float zeta = (bb - aa) * 0.5f * __builtin_amdgcn_rcpf(cc);
            float t = copysignf(__builtin_amdgcn_rcpf(fabsf(zeta) +
                          __builtin_amdgcn_sqrtf(1.f + zeta*zeta)), zeta);
            cs = __builtin_amdgcn_rsqf(1.f + t*t);
            sn = t * cs;
        }
        if(gr != total - 1){
            int par = gr & 1;
            float* MAp = P_MA(par);
            float* MBp = P_MB(par);
            // rotate & ship outgoing B first (overlap write latency with A rotation)
            float4 nb0, nb1, nb2, nb3;
            nb0.x = sn*A0.x + cs*B0.x; nb0.y = sn*A0.y + cs*B0.y;
            nb0.z = sn*A0.z + cs*B0.z; nb0.w = sn*A0.w + cs*B0.w;
            nb1.x = sn*A1.x + cs*B1.x; nb1.y = sn*A1.y + cs*B1.y;
            nb1.z = sn*A1.z + cs*B1.z; nb1.w = sn*A1.w + cs*B1.w;
            nb2.x = sn*A2.x + cs*B2.x; nb2.y = sn*A2.y + cs*B2.y;
            nb2.z = sn*A2.z + cs*B2.z; nb2.w = sn*A2.w + cs*B2.w;
            nb3.x = sn*A3.x + cs*B3.x; nb3.y = sn*A3.y + cs*B3.y;
            nb3.z = sn*A3.z + cs*B3.z; nb3.w = sn*A3.w + cs*B3.w;
            float* wb = (g == 0) ? (MAp + 1*MCS + sl*16) : (MBp + (g-1)*MCS + sl*16);
            *(float4*)(wb)      = nb0;  *(float4*)(wb + 4)  = nb1;
            *(float4*)(wb + 8)  = nb2;  *(float4*)(wb + 12) = nb3;
            float4 na0, na1, na2, na3;
            na0.x = cs*A0.x - sn*B0.x; na0.y = cs*A0.y - sn*B0.y;
            na0.z = cs*A0.z - sn*B0.z; na0.w = cs*A0.w - sn*B0.w;
            na1.x = cs*A1.x - sn*B1.x; na1.y = cs*A1.y - sn*B1.y;
            na1.z = cs*A1.z - sn*B1.z; na1.w = cs*A1.w - sn*B1.w;
            na2.x = cs*A2.x - sn*B2.x; na2.y = cs*A2.y - sn*B2.y;
            na2.z = cs*A2.z - sn*B2.z; na2.w = cs*A2.w - sn*B2.w;
            na3.x = cs*A3.x - sn*B3.x; na3.y = cs*A3.y - sn*B3.y;
            na3.z = cs*A3.z - sn*B3.z; na3.w = cs*A3.w - sn*B3.w;
            if(g >= 1 && g <= 30){
                float* wa = MAp + (g+1)*MCS + sl*16;
                *(float4*)(wa)      = na0;  *(float4*)(wa + 4)  = na1;
                *(float4*)(wa + 8)  = na2;  *(float4*)(wa + 12) = na3;
            }
            __syncthreads();
            float4 nA0=na0, nA1=na1, nA2=na2, nA3=na3;   // g==0 keeps rotated A
            float4 nB0=na0, nB1=na1, nB2=na2, nB3=na3;   // g==31: new B = rotated A
            if(g >= 1){
                const float* ra = MAp + g*MCS + sl*16;
                nA0 = *(const float4*)(ra);      nA1 = *(const float4*)(ra + 4);
                nA2 = *(const float4*)(ra + 8);  nA3 = *(const float4*)(ra + 12);
            }
            if(g <= 30){
                const float* rb = MBp + g*MCS + sl*16;
                nB0 = *(const float4*)(rb);      nB1 = *(const float4*)(rb + 4);
                nB2 = *(const float4*)(rb + 8);  nB3 = *(const float4*)(rb + 12);
            }
            A0=nA0; A1=nA1; A2=nA2; A3=nA3;
            B0=nB0; B1=nB1; B2=nB2; B3=nB3;
        } else {
            float4 na;
            #define ROT(Aq,Bq) na.x = cs*Aq.x - sn*Bq.x; na.y = cs*Aq.y - sn*Bq.y; \
                               na.z = cs*Aq.z - sn*Bq.z; na.w = cs*Aq.w - sn*Bq.w; \
                               Bq.x = sn*Aq.x + cs*Bq.x; Bq.y = sn*Aq.y + cs*Bq.y; \
                               Bq.z = sn*Aq.z + cs*Bq.z; Bq.w = sn*Aq.w + cs*Bq.w; Aq = na;
            ROT(A0,B0) ROT(A1,B1) ROT(A2,B2) ROT(A3,B3)
            #undef ROT
        }
    }
    // final column norms + store W to LDS
    {
        float fa = qsum(DOT4(A0,A0)+DOT4(A1,A1)+DOT4(A2,A2)+DOT4(A3,A3));
        float fb = qsum(DOT4(B0,B0)+DOT4(B1,B1)+DOT4(B2,B2)+DOT4(B3,B3));
        __syncthreads();   // mailbox reads done before Wc (aliases MB) written
        float* Wc = P_WC;
        float* wa = Wc + (2*g)*MCS + sl*16;
        *(float4*)(wa)      = A0;  *(float4*)(wa + 4)  = A1;
        *(float4*)(wa + 8)  = A2;  *(float4*)(wa + 12) = A3;
        float* wb = Wc + (2*g+1)*MCS + sl*16;
        *(float4*)(wb)      = B0;  *(float4*)(wb + 4)  = B1;
        *(float4*)(wb + 8)  = B2;  *(float4*)(wb + 12) = B3;
        if(sl == 0){ s2[2*g] = fa; s2[2*g+1] = fb; }
    }
    __syncthreads();
    if(tid == 0){
        float sm = 0.f;
        for(int c = 0; c < 64; ++c) sm = fmaxf(sm, s2[c]);
        smax_sh = sqrtf(sm);
    }
    __syncthreads();
    if(tid < 64){
        float s = sqrtf(s2[tid]);
        float v = vp[0];
        float tau = 0.4f / (1.f + expf(-v));     // sigmoid(v)*COEF_GAMMA
        float thr = tau * smax_sh;
        coef3[tid] = (s > thr && s > 1e-20f) ? (s - thr) / (s*s*s) : 0.f;
    }
    __syncthreads();

    const float* Wc = P_WC;
    float* Tsh = P_TSH;
    // R1: T'[k][j] = coef3[k] * sum_r Wc[k][r] * Xsh[r][j]
    for(int half = 0; half < 2; ++half){
        int kk = tid >> 1;
        int j0 = (tid & 1) * 32 + half * 16;
        float acc[16];
        #pragma unroll
        for(int j = 0; j < 16; ++j) acc[j] = 0.f;
        for(int r = 0; r < 64; ++r){
            float wk = Wc[kk*MCS + r];
            const float* xr = Xsh + r*64 + j0;
            float4 x0 = *(const float4*)(xr);
            float4 x1 = *(const float4*)(xr + 4);
            float4 x2 = *(const float4*)(xr + 8);
            float4 x3 = *(const float4*)(xr + 12);
            acc[0]+=wk*x0.x; acc[1]+=wk*x0.y; acc[2]+=wk*x0.z; acc[3]+=wk*x0.w;
            acc[4]+=wk*x1.x; acc[5]+=wk*x1.y; acc[6]+=wk*x1.z; acc[7]+=wk*x1.w;
            acc[8]+=wk*x2.x; acc[9]+=wk*x2.y; acc[10]+=wk*x2.z; acc[11]+=wk*x2.w;
            acc[12]+=wk*x3.x; acc[13]+=wk*x3.y; acc[14]+=wk*x3.z; acc[15]+=wk*x3.w;
        }
        float c3 = coef3[kk];
        float* tr = Tsh + kk*64 + j0;
        #pragma unroll
        for(int j = 0; j < 16; ++j) tr[j] = c3 * acc[j];
    }
    __syncthreads();

    // R2: Ltmp[i][j] = sum_k Wc[k][i] * T'[k][j]; outputs
    float neta = netap[0];
    for(int half = 0; half < 2; ++half){
        int i  = tid >> 1;
        int j0 = (tid & 1) * 32 + half * 16;
        float acc[16];
        #pragma unroll
        for(int j = 0; j < 16; ++j) acc[j] = 0.f;
        for(int kk = 0; kk < 64; ++kk){
            float wik = Wc[kk*MCS + i];
            const float* tr = Tsh + kk*64 + j0;
            float4 t0 = *(const float4*)(tr);
            float4 t1 = *(const float4*)(tr + 4);
            float4 t2 = *(const float4*)(tr + 8);
            float4 t3 = *(const float4*)(tr + 12);
            acc[0]+=wik*t0.x; acc[1]+=wik*t0.y; acc[2]+=wik*t0.z; acc[3]+=wik*t0.w;
            acc[4]+=wik*t1.x; acc[5]+=wik*t1.y; acc[6]+=wik*t1.z; acc[7]+=wik*t1.w;
            acc[8]+=wik*t2.x; acc[9]+=wik*t2.y; acc[10]+=wik*t2.z; acc[11]+=wik*t2.w;
            acc[12]+=wik*t3.x; acc[13]+=wik*t3.y; acc[14]+=wik*t3.z; acc[15]+=wik*t3.w;
        }
        int n0 = i*64 + j0;
        #pragma unroll
        for(int c = 0; c < 4; ++c){
            float4 th = *(const float4*)(thP + n0 + 4*c);
            float4 lt, pt;
            lt.x = acc[4*c+0]; lt.y = acc[4*c+1]; lt.z = acc[4*c+2]; lt.w = acc[4*c+3];
            float4 xs = *(const float4*)(Xsh + n0 + 4*c);
            pt.x = th.x + neta * (xs.x - th.x - lt.x);
            pt.y = th.y + neta * (xs.y - th.y - lt.y);
            pt.z = th.z + neta * (xs.z - th.z - lt.z);
            pt.w = th.w + neta * (xs.w - th.w - lt.w);
            *(float4*)(out + n0 + 4*c)      = lt;
            *(float4*)(out + NN + n0 + 4*c) = pt;
        }
    }
}

extern "C" void kernel_launch(void* const* d_in, const int* in_sizes, int n_in,
                              void* d_out, int out_size, void* d_ws, size_t ws_size,
                              hipStream_t stream){
    const float* inp  = (const float*)d_in[0];
    const float* L    = (const float*)d_in[1];
    const int*   mask = (const int*)  d_in[2];
    const float* D    = (const float*)d_in[3];
    const float* thP  = (const float*)d_in[4];
    const float* vS   = (const float*)d_in[5];
    const float* neta = (const float*)d_in[6];
    const float* l1   = (const float*)d_in[7];
    const float* l2   = (const float*)d_in[8];
    const float* rho  = (const float*)d_in[9];
    const float* S    = (const float*)d_in[10];
    float* wf = (float*)d_ws;
    float* out = (float*)d_out;
    const bool use_bf16 = (ws_size >= WS_NEED_BF16);
    unsigned short* Dh = (unsigned short*)((char*)d_ws + DH_OFF_BYTES);

    float* Xb[2] = { wf + OFF_X0, wf + OFF_X1 };
    float* Rb[2] = { wf + OFF_R0, wf + OFF_R1 };
    float* Pb[2] = { wf + OFF_P0, wf + OFF_P1 };
    float* Yb[2] = { wf + OFF_Y0, wf + OFF_Y1 };

    k_prep<<<16, 256, 0, stream>>>(inp, L, mask, thP, S, l2, rho, wf);   // also zeroes pTy slots
    if(use_bf16){
        k_step_fc<<<1024, 256, 0, stream>>>(D, Dh, l1, l2, wf, Pb[0], Yb[0], 8);
        for(int j = 1; j < NITER; ++j){
            int ro = (j+1)&1, wr = j&1;
            k_step_h<<<1024, 256, 0, stream>>>(Dh, l1, l2, wf,
                Rb[ro], Pb[ro], Xb[ro], Yb[ro],
                Rb[wr], Pb[wr], Xb[wr], Yb[wr], 8+j-1, 8+j);
        }
    } else {
        k_step_f<<<1024, 256, 0, stream>>>(D, l1, l2, wf,
            Rb[0], Pb[0], Xb[0], Yb[0], Rb[1], Pb[1], Xb[1], Yb[0], 8, 8, 0);
        for(int j = 1; j < NITER; ++j){
            int ro = (j+1)&1, wr = j&1;
            k_step_f<<<1024, 256, 0, stream>>>(D, l1, l2, wf,
                Rb[ro], Pb[ro], Xb[ro], Yb[ro],
                Rb[wr], Pb[wr], Xb[wr], Yb[wr], 8+j-1, 8+j, 1);
        }
    }
    // NITER=4 -> last write parity = (NITER-1)&1 = 1
    const int lp = (NITER-1)&1;
    k_svt<<<1, 128, 0, stream>>>(thP, vS, neta, wf, Rb[lp], Pb[lp], Xb[lp], 8+NITER-1, out);
}